// Round 10
// baseline (314.079 us; speedup 1.0000x reference)
//
#include <hip/hip_runtime.h>
#include <hip/hip_bf16.h>

constexpr int Bb = 2, Nn = 2048, Ff = 768, Hh = 8, Oo = 256;

typedef __attribute__((ext_vector_type(8)))  short   short8;
typedef __attribute__((ext_vector_type(16))) float   f32x16;
typedef __attribute__((ext_vector_type(4)))  unsigned short ushort4_t;

__device__ inline unsigned short f2bf(float f) {
    unsigned u = __float_as_uint(f);
    u = (u + 0x7FFFu + ((u >> 16) & 1u)) >> 16;   // RNE
    return (unsigned short)u;
}

// ======== B-fragment layout: frag id = nt32*(K/16)+kt, 1 KB each ========
__device__ inline void wfrag_kn_body(
        const float* __restrict__ W, unsigned short* __restrict__ out,
        int K, int N, int fblk, int t) {
    int f = fblk * 4 + (t >> 6);
    int slot = t & 63, kh = slot >> 5, lm = slot & 31;
    int nfk = K >> 4;
    int nt = f / nfk, kt = f - nt * nfk;
    const float* wp = W + (size_t)(kt * 16 + kh * 8) * N + nt * 32 + lm;
    ushort4_t o0, o1;
    o0.x = f2bf(wp[0]);             o0.y = f2bf(wp[(size_t)N]);
    o0.z = f2bf(wp[2 * (size_t)N]); o0.w = f2bf(wp[3 * (size_t)N]);
    o1.x = f2bf(wp[4 * (size_t)N]); o1.y = f2bf(wp[5 * (size_t)N]);
    o1.z = f2bf(wp[6 * (size_t)N]); o1.w = f2bf(wp[7 * (size_t)N]);
    unsigned short* op = out + (size_t)f * 512 + slot * 8;
    *(ushort4_t*)op = o0;
    *(ushort4_t*)(op + 4) = o1;
}

__device__ inline void wfrag_nk_body(
        const float* __restrict__ W, unsigned short* __restrict__ out,
        int K, int fblk, int t) {
    int f = fblk * 4 + (t >> 6);
    int slot = t & 63, kh = slot >> 5, lm = slot & 31;
    int nfk = K >> 4;
    int nt = f / nfk, kt = f - nt * nfk;
    const float* wp = W + (size_t)(nt * 32 + lm) * K + kt * 16 + kh * 8;
    float4 a = *(const float4*)wp, b = *(const float4*)(wp + 4);
    ushort4_t o0, o1;
    o0.x = f2bf(a.x); o0.y = f2bf(a.y); o0.z = f2bf(a.z); o0.w = f2bf(a.w);
    o1.x = f2bf(b.x); o1.y = f2bf(b.y); o1.z = f2bf(b.z); o1.w = f2bf(b.w);
    unsigned short* op = out + (size_t)f * 512 + slot * 8;
    *(ushort4_t*)op = o0;
    *(ushort4_t*)(op + 4) = o1;
}

// ---------------- merged prep: adjbits + x cast + all weight frag tables (1 launch) ----------------
__global__ __launch_bounds__(256) void prep_misc_kernel(
        const float* __restrict__ adj, unsigned long long* __restrict__ bits,
        const float* __restrict__ x, unsigned short* __restrict__ x_bf,
        const float* __restrict__ W_heads, unsigned short* __restrict__ WhF,
        const float* __restrict__ W_out,   unsigned short* __restrict__ WoF,
        const float* __restrict__ W_lin,   unsigned short* __restrict__ WlF,
        const float* __restrict__ W_ln,    unsigned short* __restrict__ WnF) {
    int blk = blockIdx.x, t = threadIdx.x;
    if (blk < 32768) {
        size_t gid = (size_t)blk * 256 + t;
        float v = adj[gid];
        unsigned long long m = __ballot(v > 0.f);
        if ((t & 63) == 0) bits[gid >> 6] = m;
    } else if (blk < 35840) {
        size_t i = (size_t)(blk - 32768) * 256 + t;
        float4 v = ((const float4*)x)[i];
        ushort4_t o;
        o.x = f2bf(v.x); o.y = f2bf(v.y); o.z = f2bf(v.z); o.w = f2bf(v.w);
        ((ushort4_t*)x_bf)[i] = o;
    } else if (blk < 36608) {
        int idx = blk - 35840;
        int head = idx / 96, fblk = idx - head * 96;
        wfrag_kn_body(W_heads + (size_t)head * Ff * Oo, WhF + (size_t)head * 384 * 512,
                      Ff, Oo, fblk, t);
    } else if (blk < 36864) {
        wfrag_kn_body(W_out, WoF, Hh * Oo, Oo, blk - 36608, t);
    } else if (blk < 37120) {
        wfrag_nk_body(W_lin, WlF, Hh * Oo, blk - 36864, t);
    } else {
        wfrag_nk_body(W_ln, WnF, Oo, blk - 37120, t);
    }
}

// ---------------- 32-row-tile MFMA GEMM, BK=128 (R18 verified) ----------------
template<int SWAPZ>
__global__ __launch_bounds__(256) void gemm32_kernel(
        const unsigned short* __restrict__ A, int K, long long sA, int bAshift,
        const unsigned short* __restrict__ BF, long long sB, int bmask,
        float* __restrict__ C, long long sC,
        unsigned short* __restrict__ CF, long long sCF, int Mtot,
        const float* __restrict__ bias, int mode,
        const float* __restrict__ aall, int amask,
        float* __restrict__ E1p, float* __restrict__ E1n, float2* __restrict__ E2pn) {
    int z  = SWAPZ ? blockIdx.x : blockIdx.z;
    int mx = SWAPZ ? blockIdx.y : blockIdx.x;
    A  += (size_t)(z >> bAshift) * sA;
    BF += (size_t)(z & bmask) * sB;
    if (C) C += (size_t)z * sC;
    if (CF) CF += (size_t)z * sCF;
    int m0 = mx * 32;
    int t = threadIdx.x;
    int wv = t >> 6, lane = t & 63;
    int lm = lane & 31, kh = lane >> 5;
    int nfk = K >> 4;
    __shared__ __align__(16) unsigned short As[32][136];
    f32x16 acc[2] = {};
    int sr = t >> 3, sc2 = (t & 7) * 16;
    const unsigned short* ag  = A + (size_t)(m0 + sr) * K + sc2;
    const unsigned short* bg0 = BF + (size_t)(wv * 2) * nfk * 512;
    const unsigned short* bg1 = bg0 + (size_t)nfk * 512;
    for (int k0 = 0; k0 < K; k0 += 128) {
        *(short8*)&As[sr][sc2]     = *(const short8*)(ag + k0);
        *(short8*)&As[sr][sc2 + 8] = *(const short8*)(ag + k0 + 8);
        int kt0 = k0 >> 4;
        __syncthreads();
#pragma unroll
        for (int s = 0; s < 8; ++s) {
            short8 a0 = *(const short8*)&As[lm][s * 16 + kh * 8];
            short8 b0 = *(const short8*)(bg0 + (size_t)(kt0 + s) * 512 + lane * 8);
            short8 b1 = *(const short8*)(bg1 + (size_t)(kt0 + s) * 512 + lane * 8);
            acc[0] = __builtin_amdgcn_mfma_f32_32x32x16_bf16(a0, b0, acc[0], 0, 0, 0);
            acc[1] = __builtin_amdgcn_mfma_f32_32x32x16_bf16(a0, b1, acc[1], 0, 0, 0);
        }
        __syncthreads();
    }
#pragma unroll
    for (int nt = 0; nt < 2; ++nt) {
        int colg = wv * 64 + nt * 32 + lm;
        float bv = (mode == 2) ? bias[colg] : 0.f;
        if (C) {
#pragma unroll
            for (int reg = 0; reg < 16; ++reg) {
                int rl = 4 * kh + (reg & 3) + 8 * (reg >> 2);
                float v = acc[nt][reg];
                if (mode == 2) { v += bv; v = fmaxf(v, 0.f); }
                C[(size_t)(m0 + rl) * 256 + colg] = v;
            }
        }
        if (mode == 1) {
#pragma unroll
            for (int q = 0; q < 4; ++q) {
                int kt = m0 / 16 + (q >> 1);
                size_t fi = ((size_t)(colg >> 5) * (Mtot / 16) + kt) * 512 +
                            ((q & 1) * 32 + (colg & 31)) * 8 + kh * 4;
                ushort4_t pk;
                pk.x = f2bf(acc[nt][q * 4 + 0]);
                pk.y = f2bf(acc[nt][q * 4 + 1]);
                pk.z = f2bf(acc[nt][q * 4 + 2]);
                pk.w = f2bf(acc[nt][q * 4 + 3]);
                *(ushort4_t*)(CF + fi) = pk;
            }
        }
    }
    if (aall) {
        const float* av = aall + (size_t)(z & amask) * 512;
        float a1v0 = av[wv * 64 + lm],       a1v1 = av[wv * 64 + 32 + lm];
        float a2v0 = av[256 + wv * 64 + lm], a2v1 = av[256 + wv * 64 + 32 + lm];
        float* sbuf = (float*)As;
#pragma unroll
        for (int reg = 0; reg < 16; ++reg) {
            int rl = 4 * kh + (reg & 3) + 8 * (reg >> 2);
            float v1 = acc[0][reg] * a1v0 + acc[1][reg] * a1v1;
            float v2 = acc[0][reg] * a2v0 + acc[1][reg] * a2v1;
#pragma unroll
            for (int m = 1; m <= 16; m <<= 1) {
                v1 += __shfl_xor(v1, m, 64);
                v2 += __shfl_xor(v2, m, 64);
            }
            if (lm == 0) { sbuf[rl * 8 + wv] = v1; sbuf[rl * 8 + 4 + wv] = v2; }
        }
        __syncthreads();
        if (t < 32) {
            float s1 = sbuf[t * 8] + sbuf[t * 8 + 1] + sbuf[t * 8 + 2] + sbuf[t * 8 + 3];
            float s2 = sbuf[t * 8 + 4] + sbuf[t * 8 + 5] + sbuf[t * 8 + 6] + sbuf[t * 8 + 7];
            size_t ei = (size_t)z * Nn + m0 + t;
            E1p[ei] = __expf(s1);
            E1n[ei] = __expf(0.2f * s1);
            E2pn[ei] = make_float2(__expf(s2), __expf(0.2f * s2));
        }
    }
}

// ---------------- 32-row dual GEMM, BK=128 — 8-wave blocks (2 waves/SIMD) ----------------
__global__ __launch_bounds__(512) void gemm32_dual_kernel(
        const unsigned short* __restrict__ A, int K, long long sA,
        const unsigned short* __restrict__ BF,
        unsigned short* __restrict__ h2f, float* __restrict__ lin,
        const float* __restrict__ a_out,
        float* __restrict__ E1p, float* __restrict__ E1n, float2* __restrict__ E2pn) {
    int b = blockIdx.z, ng = blockIdx.y;
    A += (size_t)b * sA;
    int nfk = K >> 4;
    BF += (size_t)ng * 8 * nfk * 512;
    int m0 = blockIdx.x * 32;
    int t = threadIdx.x;
    int wv = t >> 6, lane = t & 63;          // wv in 0..7
    int lm = lane & 31, kh = lane >> 5;
    __shared__ __align__(16) unsigned short As[32][136];
    f32x16 acc = {};
    int sr = t >> 4, sc2 = (t & 15) * 8;     // 512 threads: one short8 each
    const unsigned short* ag = A + (size_t)(m0 + sr) * K + sc2;
    const unsigned short* bg = BF + (size_t)wv * nfk * 512;
    for (int k0 = 0; k0 < K; k0 += 128) {
        *(short8*)&As[sr][sc2] = *(const short8*)(ag + k0);
        int kt0 = k0 >> 4;
        __syncthreads();
#pragma unroll
        for (int s = 0; s < 8; ++s) {
            short8 a0 = *(const short8*)&As[lm][s * 16 + kh * 8];
            short8 b0 = *(const short8*)(bg + (size_t)(kt0 + s) * 512 + lane * 8);
            acc = __builtin_amdgcn_mfma_f32_32x32x16_bf16(a0, b0, acc, 0, 0, 0);
        }
        __syncthreads();
    }
    int colg = wv * 32 + lm;
    if (ng == 1) {
        float* C = lin + (size_t)b * Nn * 256;
#pragma unroll
        for (int reg = 0; reg < 16; ++reg) {
            int rl = 4 * kh + (reg & 3) + 8 * (reg >> 2);
            C[(size_t)(m0 + rl) * 256 + colg] = acc[reg];
        }
    } else {
        unsigned short* CF = h2f + (size_t)b * 524288;
#pragma unroll
        for (int q = 0; q < 4; ++q) {
            int kt = m0 / 16 + (q >> 1);
            size_t fi = ((size_t)(colg >> 5) * 128 + kt) * 512 +
                        ((q & 1) * 32 + (colg & 31)) * 8 + kh * 4;
            ushort4_t pk;
            pk.x = f2bf(acc[q * 4 + 0]);
            pk.y = f2bf(acc[q * 4 + 1]);
            pk.z = f2bf(acc[q * 4 + 2]);
            pk.w = f2bf(acc[q * 4 + 3]);
            *(ushort4_t*)(CF + fi) = pk;
        }
        float a1v = a_out[colg];
        float a2v = a_out[256 + colg];
        float* sbuf = (float*)As;
#pragma unroll
        for (int reg = 0; reg < 16; ++reg) {
            int rl = 4 * kh + (reg & 3) + 8 * (reg >> 2);
            float v1 = acc[reg] * a1v;
            float v2 = acc[reg] * a2v;
#pragma unroll
            for (int m = 1; m <= 16; m <<= 1) {
                v1 += __shfl_xor(v1, m, 64);
                v2 += __shfl_xor(v2, m, 64);
            }
            if (lm == 0) { sbuf[rl * 16 + wv] = v1; sbuf[rl * 16 + 8 + wv] = v2; }
        }
        __syncthreads();
        if (t < 32) {
            float s1 = 0.f, s2 = 0.f;
#pragma unroll
            for (int k = 0; k < 8; ++k) {
                s1 += sbuf[t * 16 + k];
                s2 += sbuf[t * 16 + 8 + k];
            }
            size_t ei = (size_t)b * Nn + m0 + t;
            E1p[ei] = __expf(s1);
            E1n[ei] = __expf(0.2f * s1);
            E2pn[ei] = make_float2(__expf(s2), __expf(0.2f * s2));
        }
    }
}

// ---------------- final GEMM with fused combine, BK=128, o-split x2 ----------------
__global__ __launch_bounds__(256) void gemm32_final_kernel(
        const float* __restrict__ pacc, const float* __restrict__ plsum,
        const float* __restrict__ lin, const float* __restrict__ b_lin,
        const unsigned short* __restrict__ BF, const float* __restrict__ b_ln,
        float* __restrict__ out) {
    int b = blockIdx.z, oc = blockIdx.y;
    int m0 = blockIdx.x * 32;
    int t = threadIdx.x;
    int wv = t >> 6, lane = t & 63;
    int lm = lane & 31, kh = lane >> 5;
    constexpr int nfk = 16;   // K = 256
    __shared__ __align__(16) unsigned short As[32][136];
    f32x16 acc = {};
    int sr = t >> 3, sc2 = (t & 7) * 16;
    int row = m0 + sr;
    int BN = Bb * Nn;
    size_t prow = (size_t)b * Nn + row;
    float li = 1.f / (plsum[prow] + plsum[prow + BN] + plsum[prow + 2 * BN] + plsum[prow + 3 * BN]);
    size_t ps4 = (size_t)Bb * Nn * 256;
    const unsigned short* bg = BF + (size_t)(oc * 4 + wv) * nfk * 512;
    for (int k0 = 0; k0 < 256; k0 += 128) {
        int o = k0 + sc2;
        size_t pidx = prow * 256 + o;
#pragma unroll
        for (int g = 0; g < 4; ++g) {
            float4 s4 = *(const float4*)(pacc + pidx + 4 * g);
#pragma unroll
            for (int k = 1; k < 4; ++k) {
                float4 q = *(const float4*)(pacc + k * ps4 + pidx + 4 * g);
                s4.x += q.x; s4.y += q.y; s4.z += q.z; s4.w += q.w;
            }
            float4 lv = *(const float4*)(lin + pidx + 4 * g);
            float4 bv = *(const float4*)(b_lin + o + 4 * g);
            ushort4_t pk;
            pk.x = f2bf(s4.x * li + lv.x + bv.x);
            pk.y = f2bf(s4.y * li + lv.y + bv.y);
            pk.z = f2bf(s4.z * li + lv.z + bv.z);
            pk.w = f2bf(s4.w * li + lv.w + bv.w);
            *(ushort4_t*)&As[sr][sc2 + 4 * g] = pk;
        }
        int kt0 = k0 >> 4;
        __syncthreads();
#pragma unroll
        for (int s = 0; s < 8; ++s) {
            short8 a0 = *(const short8*)&As[lm][s * 16 + kh * 8];
            short8 b0 = *(const short8*)(bg + (size_t)(kt0 + s) * 512 + lane * 8);
            acc = __builtin_amdgcn_mfma_f32_32x32x16_bf16(a0, b0, acc, 0, 0, 0);
        }
        __syncthreads();
    }
    float* C = out + (size_t)b * Nn * 256;
    int colg = oc * 128 + wv * 32 + lm;
    float bv = b_ln[colg];
#pragma unroll
    for (int reg = 0; reg < 16; ++reg) {
        int rl = 4 * kh + (reg & 3) + 8 * (reg >> 2);
        float v = fmaxf(acc[reg] + bv, 0.f);
        C[(size_t)(m0 + rl) * 256 + colg] = v;
    }
}

// ---------------- attention 32-row (R1-verified v9: 4-slot rotation + setprio) ----------------
template<int JLEN, int MODE, int SWAPXY>
__global__ __launch_bounds__(256, 4) void attn32_kernel(
        const unsigned short* __restrict__ hfrag,
        const unsigned* __restrict__ bits,
        const float* __restrict__ E1p, const float* __restrict__ E1n,
        const float2* __restrict__ E2pn,
        unsigned short* __restrict__ outbf, int ldo,
        float* __restrict__ pacc, float* __restrict__ plsum,
        int hshift) {
    constexpr int W = JLEN / 32, NC = JLEN / 64, ABS = W + 1;
    int it = SWAPXY ? blockIdx.y : blockIdx.x;
    int bh = SWAPXY ? blockIdx.x : blockIdx.y;
    int js = blockIdx.z;
    int b = bh >> hshift, hd = bh & ((1 << hshift) - 1);
    int i0 = it * 32, jbase = js * JLEN;
    int kt0 = js * (JLEN / 16);
    int t = threadIdx.x, lane = t & 63;
    int wv = t >> 6, lm = lane & 31, kh = lane >> 5;
    int ti = t & 31, jq = t >> 5;

    __shared__ unsigned ab[32 * ABS];
    __shared__ __align__(16) unsigned short ps[2][32][64];
    __shared__ float lred[32][9];
    __shared__ float linv[32];

    const unsigned* bb = bits + ((size_t)b * Nn + i0) * 64 + (jbase >> 5);
    for (int k = t; k < 32 * W; k += 256) {
        int r = k / W, w0 = k - r * W;
        ab[r * ABS + w0] = bb[(size_t)r * 64 + w0];
    }
    __syncthreads();

    float e1p = E1p[(size_t)bh * Nn + i0 + ti];
    float e1n = E1n[(size_t)bh * Nn + i0 + ti];
    const float4* e2base = (const float4*)(E2pn + (size_t)bh * Nn + jbase);

    const unsigned short* bg0 = hfrag + (size_t)bh * 524288 + (size_t)(wv * 2) * 128 * 512;
    const unsigned short* bg1 = bg0 + 128 * 512;

    f32x16 acc[2] = {};
    float lp0 = 0.f, lp1 = 0.f;
    short8 Bpp[4][2];

    auto loadBs = [&](int c, int s, int slot) {
        int kt = kt0 + c * 4 + s;
        Bpp[slot][0] = *(const short8*)(bg0 + (size_t)kt * 512 + lane * 8);
        Bpp[slot][1] = *(const short8*)(bg1 + (size_t)kt * 512 + lane * 8);
    };
    auto computeP = [&](int c, int buf) {
        int cj = c * 64;
        unsigned word = ab[ti * ABS + (cj >> 5) + (jq >> 2)];
        unsigned field = (word >> ((jq & 3) * 8)) & 0xffu;
        const float4* ep = e2base + ((cj + jq * 8) >> 1);
        unsigned pk[4];
#pragma unroll
        for (int u = 0; u < 4; ++u) {
            float4 q = ep[u];
            float p0 = fmaxf(e1p * q.x, e1n * q.y);
            p0 = ((field >> (2 * u)) & 1u) ? p0 : 0.f;
            float p1 = fmaxf(e1p * q.z, e1n * q.w);
            p1 = ((field >> (2 * u + 1)) & 1u) ? p1 : 0.f;
            if (u & 1) lp1 += p0 + p1; else lp0 += p0 + p1;
            __hip_bfloat162 hv = __float22bfloat162_rn(make_float2(p0, p1));
            pk[u] = *(unsigned*)&hv;
        }
        uint4 v; v.x = pk[0]; v.y = pk[1]; v.z = pk[2]; v.w = pk[3];
        *(uint4*)&ps[buf][ti][(jq ^ (ti & 7)) * 8] = v;
    };
    auto mfmaS = [&](int buf, int s, int slot) {
        int g = 2 * s + kh;
        short8 a0 = *(const short8*)&ps[buf][lm][(g ^ (lm & 7)) * 8];
        __builtin_amdgcn_s_setprio(1);
        acc[0] = __builtin_amdgcn_mfma_f32_32x32x16_bf16(a0, Bpp[slot][0], acc[0], 0, 0, 0);
        acc[1] = __builtin_amdgcn_mfma_f32_32x32x16_bf16(a0, Bpp[slot][1], acc[1], 0, 0, 0);
        __builtin_amdgcn_s_setprio(0);
    };

    computeP(0, 0);
    loadBs(0, 0, 0); loadBs(0, 1, 1); loadBs(0, 2, 2); loadBs(0, 3, 3);
    __syncthreads();
    for (int c = 0; c + 1 < NC; ++c) {
        int cb = c & 1, nb = cb ^ 1;
        computeP(c + 1, nb);
        mfmaS(cb, 0, 0);  loadBs(c + 1, 0, 0);
        mfmaS(cb, 1, 1);  loadBs(c + 1, 1, 1);
        mfmaS(cb, 2, 2);  loadBs(c + 1, 2, 2);
        mfmaS(cb, 3, 3);  loadBs(c + 1, 3, 3);
        __syncthreads();
    }
    {
        int cb = (NC - 1) & 1;
        mfmaS(cb, 0, 0);
        mfmaS(cb, 1, 1);
        mfmaS(cb, 2, 2);
        mfmaS(cb, 3, 3);
    }

    lred[ti][jq] = lp0 + lp1;
    __syncthreads();
    if (MODE == 0) {
        if (t < 32) {
            float s = 0.f;
#pragma unroll
            for (int k = 0; k < 8; ++k) s += lred[t][k];
            linv[t] = 1.f / s;
        }
        __syncthreads();
#pragma unroll
        for (int nt = 0; nt < 2; ++nt) {
            int o = wv * 64 + nt * 32 + lm;
#pragma unroll
            for (int reg = 0; reg < 16; ++reg) {
                int rl = 4 * kh + (reg & 3) + 8 * (reg >> 2);
                float v = acc[nt][reg] * linv[rl];
                v = v > 0.f ? v : expm1f(v);
                outbf[((size_t)b * Nn + i0 + rl) * ldo + (size_t)hd * Oo + o] = f2bf(v);
            }
        }
    } else {
        if (t < 32) {
            float s = 0.f;
#pragma unroll
            for (int k = 0; k < 8; ++k) s += lred[t][k];
            plsum[((size_t)js * Bb + b) * Nn + i0 + t] = s;
        }
        float* pa = pacc + (((size_t)js * Bb + b) * Nn) * 256;
#pragma unroll
        for (int nt = 0; nt < 2; ++nt) {
            int o = wv * 64 + nt * 32 + lm;
#pragma unroll
            for (int reg = 0; reg < 16; ++reg) {
                int rl = 4 * kh + (reg & 3) + 8 * (reg >> 2);
                pa[(size_t)(i0 + rl) * 256 + o] = acc[nt][reg];
            }
        }
    }
}

// ---------------- attention 64-row: R6 structure + 2-deep e2 register prefetch ----------------
// e2 loads for chunk c+2 are issued at the top of iteration c and consumed by computeP in
// iteration c+1 — a full chunk (computeP + 4 mfmaS + barrier) of latency cover. Safe here:
// launch_bounds(256,2) gives a 256-VGPR cap (76 used), unlike the 128-cap kernels where
// this buffer spilled (R2/R4 lessons).
template<int JLEN, int MODE, int SWAPXY>
__global__ __launch_bounds__(256, 2) void attn64_kernel(
        const unsigned short* __restrict__ hfrag,
        const unsigned* __restrict__ bits,
        const float* __restrict__ E1p, const float* __restrict__ E1n,
        const float2* __restrict__ E2pn,
        unsigned short* __restrict__ outbf, int ldo,
        float* __restrict__ pacc, float* __restrict__ plsum,
        int hshift) {
    constexpr int W = JLEN / 32, NC = JLEN / 64, ABS = W + 1;
    int it = SWAPXY ? blockIdx.y : blockIdx.x;
    int bh = SWAPXY ? blockIdx.x : blockIdx.y;
    int js = blockIdx.z;
    int b = bh >> hshift, hd = bh & ((1 << hshift) - 1);
    int i0 = it * 64, jbase = js * JLEN;
    int kt0 = js * (JLEN / 16);
    int t = threadIdx.x, lane = t & 63;
    int wv = t >> 6, lm = lane & 31, kh = lane >> 5;
    int ti = t & 31, jq = t >> 5;

    __shared__ unsigned ab[64 * ABS];
    __shared__ __align__(16) unsigned short ps[2][64][64];
    __shared__ float lred[64][9];
    __shared__ float linv[64];

    const unsigned* bb = bits + ((size_t)b * Nn + i0) * 64 + (jbase >> 5);
    for (int k = t; k < 64 * W; k += 256) {
        int r = k / W, w0 = k - r * W;
        ab[r * ABS + w0] = bb[(size_t)r * 64 + w0];
    }
    __syncthreads();

    float e1pA = E1p[(size_t)bh * Nn + i0 + ti];
    float e1nA = E1n[(size_t)bh * Nn + i0 + ti];
    float e1pB = E1p[(size_t)bh * Nn + i0 + 32 + ti];
    float e1nB = E1n[(size_t)bh * Nn + i0 + 32 + ti];
    const float4* e2base = (const float4*)(E2pn + (size_t)bh * Nn + jbase);

    const unsigned short* bg0 = hfrag + (size_t)bh * 524288 + (size_t)(wv * 2) * 128 * 512;
    const unsigned short* bg1 = bg0 + 128 * 512;

    f32x16 acc[4] = {};
    float lpA = 0.f, lpB = 0.f;
    short8 Bpp[4][2];
    float4 e2a[4], e2b[4];   // 2-deep e2 pipeline (chunk k lives in buf[k&1])

    auto loadE2 = [&](int c, float4 (&e2)[4]) {
        const float4* ep = e2base + ((c * 64 + jq * 8) >> 1);
#pragma unroll
        for (int u = 0; u < 4; ++u) e2[u] = ep[u];
    };
    auto loadBs = [&](int c, int s, int slot) {
        int kt = kt0 + c * 4 + s;
        Bpp[slot][0] = *(const short8*)(bg0 + (size_t)kt * 512 + lane * 8);
        Bpp[slot][1] = *(const short8*)(bg1 + (size_t)kt * 512 + lane * 8);
    };
    auto computeP = [&](int c, int buf, const float4 (&e2)[4]) {
        int cj = c * 64;
        int wi = (cj >> 5) + (jq >> 2);
        unsigned wordA = ab[ti * ABS + wi];
        unsigned wordB = ab[(ti + 32) * ABS + wi];
        unsigned fieldA = (wordA >> ((jq & 3) * 8)) & 0xffu;
        unsigned fieldB = (wordB >> ((jq & 3) * 8)) & 0xffu;
        unsigned pkA[4], pkB[4];
#pragma unroll
        for (int u = 0; u < 4; ++u) {
            float4 q = e2[u];   // shared between both rows, preloaded 1 chunk ago
            float a0v = fmaxf(e1pA * q.x, e1nA * q.y);
            a0v = ((fieldA >> (2 * u)) & 1u) ? a0v : 0.f;
            float a1v = fmaxf(e1pA * q.z, e1nA * q.w);
            a1v = ((fieldA >> (2 * u + 1)) & 1u) ? a1v : 0.f;
            lpA += a0v + a1v;
            float b0v = fmaxf(e1pB * q.x, e1nB * q.y);
            b0v = ((fieldB >> (2 * u)) & 1u) ? b0v : 0.f;
            float b1v = fmaxf(e1pB * q.z, e1nB * q.w);
            b1v = ((fieldB >> (2 * u + 1)) & 1u) ? b1v : 0.f;
            lpB += b0v + b1v;
            __hip_bfloat162 hA = __float22bfloat162_rn(make_float2(a0v, a1v));
            __hip_bfloat162 hB = __float22bfloat162_rn(make_float2(b0v, b1v));
            pkA[u] = *(unsigned*)&hA;
            pkB[u] = *(unsigned*)&hB;
        }
        int col = (jq ^ (ti & 7)) * 8;
        uint4 vA; vA.x = pkA[0]; vA.y = pkA[1]; vA.z = pkA[2]; vA.w = pkA[3];
        uint4 vB; vB.x = pkB[0]; vB.y = pkB[1]; vB.z = pkB[2]; vB.w = pkB[3];
        *(uint4*)&ps[buf][ti][col] = vA;
        *(uint4*)&ps[buf][ti + 32][col] = vB;
    };
    auto mfmaS = [&](int buf, int s, int slot) {
        int g = 2 * s + kh;
        int col = (g ^ (lm & 7)) * 8;
        short8 a0 = *(const short8*)&ps[buf][lm][col];
        short8 a1 = *(const short8*)&ps[buf][32 + lm][col];
        __builtin_amdgcn_s_setprio(1);
        acc[0] = __builtin_amdgcn_mfma_f32_32x32x16_bf16(a0, Bpp[slot][0], acc[0], 0, 0, 0);
        acc[1] = __builtin_amdgcn_mfma_f32_32x32x16_bf16(a0, Bpp[slot][1], acc[1], 0, 0, 0);
        acc[2] = __builtin_amdgcn_mfma_f32_32x32x16_bf16(a1, Bpp[slot][0], acc[2], 0, 0, 0);
        acc[3] = __builtin_amdgcn_mfma_f32_32x32x16_bf16(a1, Bpp[slot][1], acc[3], 0, 0, 0);
        __builtin_amdgcn_s_setprio(0);
    };

    loadE2(0, e2a);             // chunk 0 -> buf0
    loadE2(1, e2b);             // chunk 1 -> buf1
    computeP(0, 0, e2a);
    loadBs(0, 0, 0); loadBs(0, 1, 1); loadBs(0, 2, 2); loadBs(0, 3, 3);
    __syncthreads();
    for (int c = 0; c + 1 < NC; ++c) {
        int cb = c & 1, nb = cb ^ 1;
        // chunk c+2 -> buf[c&1] (holds chunk c, consumed last iteration)
        if (c + 2 < NC) loadE2(c + 2, (c & 1) ? e2b : e2a);
        // chunk c+1 lives in buf[(c+1)&1], loaded one full chunk ago
        computeP(c + 1, nb, (c & 1) ? e2a : e2b);
        mfmaS(cb, 0, 0);  loadBs(c + 1, 0, 0);
        mfmaS(cb, 1, 1);  loadBs(c + 1, 1, 1);
        mfmaS(cb, 2, 2);  loadBs(c + 1, 2, 2);
        mfmaS(cb, 3, 3);  loadBs(c + 1, 3, 3);
        __syncthreads();
    }
    {
        int cb = (NC - 1) & 1;
        mfmaS(cb, 0, 0);
        mfmaS(cb, 1, 1);
        mfmaS(cb, 2, 2);
        mfmaS(cb, 3, 3);
    }

    lred[ti][jq] = lpA;
    lred[ti + 32][jq] = lpB;
    __syncthreads();
    if (MODE == 0) {
        if (t < 64) {
            float s = 0.f;
#pragma unroll
            for (int k = 0; k < 8; ++k) s += lred[t][k];
            linv[t] = 1.f / s;
        }
        __syncthreads();
#pragma unroll
        for (int ih = 0; ih < 2; ++ih) {
#pragma unroll
            for (int nt = 0; nt < 2; ++nt) {
                int o = wv * 64 + nt * 32 + lm;
#pragma unroll
                for (int reg = 0; reg < 16; ++reg) {
                    int rl = 4 * kh + (reg & 3) + 8 * (reg >> 2);
                    int row = ih * 32 + rl;
                    float v = acc[ih * 2 + nt][reg] * linv[row];
                    v = v > 0.f ? v : expm1f(v);
                    outbf[((size_t)b * Nn + i0 + row) * ldo + (size_t)hd * Oo + o] = f2bf(v);
                }
            }
        }
    } else {
        if (t < 64) {
            float s = 0.f;
#pragma unroll
            for (int k = 0; k < 8; ++k) s += lred[t][k];
            plsum[((size_t)js * Bb + b) * Nn + i0 + t] = s;
        }
        float* pa = pacc + (((size_t)js * Bb + b) * Nn) * 256;
#pragma unroll
        for (int ih = 0; ih < 2; ++ih) {
#pragma unroll
            for (int nt = 0; nt < 2; ++nt) {
                int o = wv * 64 + nt * 32 + lm;
#pragma unroll
                for (int reg = 0; reg < 16; ++reg) {
                    int rl = 4 * kh + (reg & 3) + 8 * (reg >> 2);
                    int row = ih * 32 + rl;
                    pa[(size_t)(i0 + row) * 256 + o] = acc[ih * 2 + nt][reg];
                }
            }
        }
    }
}

extern "C" void kernel_launch(void* const* d_in, const int* in_sizes, int n_in,
                              void* d_out, int out_size, void* d_ws, size_t ws_size,
                              hipStream_t stream) {
    const float* x       = (const float*)d_in[0];
    const float* adj     = (const float*)d_in[1];
    const float* W_heads = (const float*)d_in[3];
    const float* a_heads = (const float*)d_in[4];
    const float* W_out   = (const float*)d_in[5];
    const float* a_out   = (const float*)d_in[6];
    const float* W_lin   = (const float*)d_in[7];
    const float* b_lin   = (const float*)d_in[8];
    const float* W_ln    = (const float*)d_in[9];
    const float* b_ln    = (const float*)d_in[10];

    char* w = (char*)d_ws;
    float* pacc     = (float*)(w);                    // 4x4 MB (sh partials)
    float* lin      = (float*)(w + 33554432);
    float* E1p_mh   = (float*)(w + 41943040);
    float* E1n_mh   = (float*)(w + 42074112);
    float2* E2pn_mh = (float2*)(w + 42205184);
    float* E1p_sh   = (float*)(w + 42467328);
    float* E1n_sh   = (float*)(w + 42483712);
    float2* E2pn_sh = (float2*)(w + 42500096);
    unsigned long long* bits = (unsigned long long*)(w + 42532864);
    unsigned short* x_bf  = (unsigned short*)(w + 43581440);
    unsigned short* WhF   = (unsigned short*)(w + 49872896);
    unsigned short* WoF   = (unsigned short*)(w + 53018624);
    unsigned short* WlF   = (unsigned short*)(w + 54067200);
    unsigned short* WnF   = (unsigned short*)(w + 55115776);
    unsigned short* hfrag = (unsigned short*)(w + 55246848);   // 16 MB
    unsigned short* h2frag= (unsigned short*)(w + 72024064);   // 2 MB
    unsigned short* x1_bf = (unsigned short*)(w + 74121216);
    float* plsum = E1p_mh;

    // 0) merged prep: adjbits + x cast + all weight frags (1 launch)
    prep_misc_kernel<<<37152, 256, 0, stream>>>(
        adj, bits, x, x_bf, W_heads, WhF, W_out, WoF, W_lin, WlF, W_ln, WnF);

    // 1) h = x @ W_heads -> hfrag + fused mh scores/exp (z-major: XCD = z%8)
    gemm32_kernel<1><<<dim3(Bb * Hh, Nn / 32, 1), 256, 0, stream>>>(
        x_bf, Ff, (long long)Nn * Ff, 3, WhF, 384LL * 512, 7,
        nullptr, 0, hfrag, 524288, Nn, nullptr, 1,
        a_heads, 7, E1p_mh, E1n_mh, E2pn_mh);
    // 2) multihead attention + elu -> x1_bf  (64-row tiles + 2-deep e2 prefetch)
    attn64_kernel<2048, 0, 1><<<dim3(Bb * Hh, Nn / 64, 1), 256, 0, stream>>>(
        hfrag, (const unsigned*)bits, E1p_mh, E1n_mh, E2pn_mh,
        x1_bf, Hh * Oo, nullptr, nullptr, 3);
    // 3) fused dual GEMM: h2frag (+sh scores) and lin — 8-wave blocks
    gemm32_dual_kernel<<<dim3(Nn / 32, 2, Bb), 512, 0, stream>>>(
        x1_bf, Hh * Oo, (long long)Nn * Hh * Oo, WoF, h2frag, lin,
        a_out, E1p_sh, E1n_sh, E2pn_sh);
    // 4) single-head attention, 4-way j-split partials (32-row, 2 blocks/CU)
    attn32_kernel<512, 1, 0><<<dim3(Nn / 32, Bb, 4), 256, 0, stream>>>(
        h2frag, (const unsigned*)bits, E1p_sh, E1n_sh, E2pn_sh,
        nullptr, 0, pacc, plsum, 0);
    // 5) final GEMM with fused combine (o-split x2) -> d_out
    gemm32_final_kernel<<<dim3(Nn / 32, 2, Bb), 256, 0, stream>>>(
        pacc, plsum, lin, b_lin, WnF, b_ln, (float*)d_out);
}

// Round 11
// 237.433 us; speedup vs baseline: 1.3228x; 1.3228x over previous
//
#include <hip/hip_runtime.h>
#include <hip/hip_bf16.h>

constexpr int Bb = 2, Nn = 2048, Ff = 768, Hh = 8, Oo = 256;

typedef __attribute__((ext_vector_type(8)))  short   short8;
typedef __attribute__((ext_vector_type(16))) float   f32x16;
typedef __attribute__((ext_vector_type(4)))  unsigned short ushort4_t;

__device__ inline unsigned short f2bf(float f) {
    unsigned u = __float_as_uint(f);
    u = (u + 0x7FFFu + ((u >> 16) & 1u)) >> 16;   // RNE
    return (unsigned short)u;
}

// ======== B-fragment layout: frag id = nt32*(K/16)+kt, 1 KB each ========
__device__ inline void wfrag_kn_body(
        const float* __restrict__ W, unsigned short* __restrict__ out,
        int K, int N, int fblk, int t) {
    int f = fblk * 4 + (t >> 6);
    int slot = t & 63, kh = slot >> 5, lm = slot & 31;
    int nfk = K >> 4;
    int nt = f / nfk, kt = f - nt * nfk;
    const float* wp = W + (size_t)(kt * 16 + kh * 8) * N + nt * 32 + lm;
    ushort4_t o0, o1;
    o0.x = f2bf(wp[0]);             o0.y = f2bf(wp[(size_t)N]);
    o0.z = f2bf(wp[2 * (size_t)N]); o0.w = f2bf(wp[3 * (size_t)N]);
    o1.x = f2bf(wp[4 * (size_t)N]); o1.y = f2bf(wp[5 * (size_t)N]);
    o1.z = f2bf(wp[6 * (size_t)N]); o1.w = f2bf(wp[7 * (size_t)N]);
    unsigned short* op = out + (size_t)f * 512 + slot * 8;
    *(ushort4_t*)op = o0;
    *(ushort4_t*)(op + 4) = o1;
}

__device__ inline void wfrag_nk_body(
        const float* __restrict__ W, unsigned short* __restrict__ out,
        int K, int fblk, int t) {
    int f = fblk * 4 + (t >> 6);
    int slot = t & 63, kh = slot >> 5, lm = slot & 31;
    int nfk = K >> 4;
    int nt = f / nfk, kt = f - nt * nfk;
    const float* wp = W + (size_t)(nt * 32 + lm) * K + kt * 16 + kh * 8;
    float4 a = *(const float4*)wp, b = *(const float4*)(wp + 4);
    ushort4_t o0, o1;
    o0.x = f2bf(a.x); o0.y = f2bf(a.y); o0.z = f2bf(a.z); o0.w = f2bf(a.w);
    o1.x = f2bf(b.x); o1.y = f2bf(b.y); o1.z = f2bf(b.z); o1.w = f2bf(b.w);
    unsigned short* op = out + (size_t)f * 512 + slot * 8;
    *(ushort4_t*)op = o0;
    *(ushort4_t*)(op + 4) = o1;
}

// ---------------- merged prep: adjbits + x cast + all weight frag tables (1 launch) ----------------
__global__ __launch_bounds__(256) void prep_misc_kernel(
        const float* __restrict__ adj, unsigned long long* __restrict__ bits,
        const float* __restrict__ x, unsigned short* __restrict__ x_bf,
        const float* __restrict__ W_heads, unsigned short* __restrict__ WhF,
        const float* __restrict__ W_out,   unsigned short* __restrict__ WoF,
        const float* __restrict__ W_lin,   unsigned short* __restrict__ WlF,
        const float* __restrict__ W_ln,    unsigned short* __restrict__ WnF) {
    int blk = blockIdx.x, t = threadIdx.x;
    if (blk < 32768) {
        size_t gid = (size_t)blk * 256 + t;
        float v = adj[gid];
        unsigned long long m = __ballot(v > 0.f);
        if ((t & 63) == 0) bits[gid >> 6] = m;
    } else if (blk < 35840) {
        size_t i = (size_t)(blk - 32768) * 256 + t;
        float4 v = ((const float4*)x)[i];
        ushort4_t o;
        o.x = f2bf(v.x); o.y = f2bf(v.y); o.z = f2bf(v.z); o.w = f2bf(v.w);
        ((ushort4_t*)x_bf)[i] = o;
    } else if (blk < 36608) {
        int idx = blk - 35840;
        int head = idx / 96, fblk = idx - head * 96;
        wfrag_kn_body(W_heads + (size_t)head * Ff * Oo, WhF + (size_t)head * 384 * 512,
                      Ff, Oo, fblk, t);
    } else if (blk < 36864) {
        wfrag_kn_body(W_out, WoF, Hh * Oo, Oo, blk - 36608, t);
    } else if (blk < 37120) {
        wfrag_nk_body(W_lin, WlF, Hh * Oo, blk - 36864, t);
    } else {
        wfrag_nk_body(W_ln, WnF, Oo, blk - 37120, t);
    }
}

// ---------------- 32-row-tile MFMA GEMM, BK=128 (R18 verified) ----------------
template<int SWAPZ>
__global__ __launch_bounds__(256) void gemm32_kernel(
        const unsigned short* __restrict__ A, int K, long long sA, int bAshift,
        const unsigned short* __restrict__ BF, long long sB, int bmask,
        float* __restrict__ C, long long sC,
        unsigned short* __restrict__ CF, long long sCF, int Mtot,
        const float* __restrict__ bias, int mode,
        const float* __restrict__ aall, int amask,
        float* __restrict__ E1p, float* __restrict__ E1n, float2* __restrict__ E2pn) {
    int z  = SWAPZ ? blockIdx.x : blockIdx.z;
    int mx = SWAPZ ? blockIdx.y : blockIdx.x;
    A  += (size_t)(z >> bAshift) * sA;
    BF += (size_t)(z & bmask) * sB;
    if (C) C += (size_t)z * sC;
    if (CF) CF += (size_t)z * sCF;
    int m0 = mx * 32;
    int t = threadIdx.x;
    int wv = t >> 6, lane = t & 63;
    int lm = lane & 31, kh = lane >> 5;
    int nfk = K >> 4;
    __shared__ __align__(16) unsigned short As[32][136];
    f32x16 acc[2] = {};
    int sr = t >> 3, sc2 = (t & 7) * 16;
    const unsigned short* ag  = A + (size_t)(m0 + sr) * K + sc2;
    const unsigned short* bg0 = BF + (size_t)(wv * 2) * nfk * 512;
    const unsigned short* bg1 = bg0 + (size_t)nfk * 512;
    for (int k0 = 0; k0 < K; k0 += 128) {
        *(short8*)&As[sr][sc2]     = *(const short8*)(ag + k0);
        *(short8*)&As[sr][sc2 + 8] = *(const short8*)(ag + k0 + 8);
        int kt0 = k0 >> 4;
        __syncthreads();
#pragma unroll
        for (int s = 0; s < 8; ++s) {
            short8 a0 = *(const short8*)&As[lm][s * 16 + kh * 8];
            short8 b0 = *(const short8*)(bg0 + (size_t)(kt0 + s) * 512 + lane * 8);
            short8 b1 = *(const short8*)(bg1 + (size_t)(kt0 + s) * 512 + lane * 8);
            acc[0] = __builtin_amdgcn_mfma_f32_32x32x16_bf16(a0, b0, acc[0], 0, 0, 0);
            acc[1] = __builtin_amdgcn_mfma_f32_32x32x16_bf16(a0, b1, acc[1], 0, 0, 0);
        }
        __syncthreads();
    }
#pragma unroll
    for (int nt = 0; nt < 2; ++nt) {
        int colg = wv * 64 + nt * 32 + lm;
        float bv = (mode == 2) ? bias[colg] : 0.f;
        if (C) {
#pragma unroll
            for (int reg = 0; reg < 16; ++reg) {
                int rl = 4 * kh + (reg & 3) + 8 * (reg >> 2);
                float v = acc[nt][reg];
                if (mode == 2) { v += bv; v = fmaxf(v, 0.f); }
                C[(size_t)(m0 + rl) * 256 + colg] = v;
            }
        }
        if (mode == 1) {
#pragma unroll
            for (int q = 0; q < 4; ++q) {
                int kt = m0 / 16 + (q >> 1);
                size_t fi = ((size_t)(colg >> 5) * (Mtot / 16) + kt) * 512 +
                            ((q & 1) * 32 + (colg & 31)) * 8 + kh * 4;
                ushort4_t pk;
                pk.x = f2bf(acc[nt][q * 4 + 0]);
                pk.y = f2bf(acc[nt][q * 4 + 1]);
                pk.z = f2bf(acc[nt][q * 4 + 2]);
                pk.w = f2bf(acc[nt][q * 4 + 3]);
                *(ushort4_t*)(CF + fi) = pk;
            }
        }
    }
    if (aall) {
        const float* av = aall + (size_t)(z & amask) * 512;
        float a1v0 = av[wv * 64 + lm],       a1v1 = av[wv * 64 + 32 + lm];
        float a2v0 = av[256 + wv * 64 + lm], a2v1 = av[256 + wv * 64 + 32 + lm];
        float* sbuf = (float*)As;
#pragma unroll
        for (int reg = 0; reg < 16; ++reg) {
            int rl = 4 * kh + (reg & 3) + 8 * (reg >> 2);
            float v1 = acc[0][reg] * a1v0 + acc[1][reg] * a1v1;
            float v2 = acc[0][reg] * a2v0 + acc[1][reg] * a2v1;
#pragma unroll
            for (int m = 1; m <= 16; m <<= 1) {
                v1 += __shfl_xor(v1, m, 64);
                v2 += __shfl_xor(v2, m, 64);
            }
            if (lm == 0) { sbuf[rl * 8 + wv] = v1; sbuf[rl * 8 + 4 + wv] = v2; }
        }
        __syncthreads();
        if (t < 32) {
            float s1 = sbuf[t * 8] + sbuf[t * 8 + 1] + sbuf[t * 8 + 2] + sbuf[t * 8 + 3];
            float s2 = sbuf[t * 8 + 4] + sbuf[t * 8 + 5] + sbuf[t * 8 + 6] + sbuf[t * 8 + 7];
            size_t ei = (size_t)z * Nn + m0 + t;
            E1p[ei] = __expf(s1);
            E1n[ei] = __expf(0.2f * s1);
            E2pn[ei] = make_float2(__expf(s2), __expf(0.2f * s2));
        }
    }
}

// ---------------- 32-row dual GEMM, BK=128 — 8-wave blocks (2 waves/SIMD) ----------------
__global__ __launch_bounds__(512) void gemm32_dual_kernel(
        const unsigned short* __restrict__ A, int K, long long sA,
        const unsigned short* __restrict__ BF,
        unsigned short* __restrict__ h2f, float* __restrict__ lin,
        const float* __restrict__ a_out,
        float* __restrict__ E1p, float* __restrict__ E1n, float2* __restrict__ E2pn) {
    int b = blockIdx.z, ng = blockIdx.y;
    A += (size_t)b * sA;
    int nfk = K >> 4;
    BF += (size_t)ng * 8 * nfk * 512;
    int m0 = blockIdx.x * 32;
    int t = threadIdx.x;
    int wv = t >> 6, lane = t & 63;          // wv in 0..7
    int lm = lane & 31, kh = lane >> 5;
    __shared__ __align__(16) unsigned short As[32][136];
    f32x16 acc = {};
    int sr = t >> 4, sc2 = (t & 15) * 8;     // 512 threads: one short8 each
    const unsigned short* ag = A + (size_t)(m0 + sr) * K + sc2;
    const unsigned short* bg = BF + (size_t)wv * nfk * 512;
    for (int k0 = 0; k0 < K; k0 += 128) {
        *(short8*)&As[sr][sc2] = *(const short8*)(ag + k0);
        int kt0 = k0 >> 4;
        __syncthreads();
#pragma unroll
        for (int s = 0; s < 8; ++s) {
            short8 a0 = *(const short8*)&As[lm][s * 16 + kh * 8];
            short8 b0 = *(const short8*)(bg + (size_t)(kt0 + s) * 512 + lane * 8);
            acc = __builtin_amdgcn_mfma_f32_32x32x16_bf16(a0, b0, acc, 0, 0, 0);
        }
        __syncthreads();
    }
    int colg = wv * 32 + lm;
    if (ng == 1) {
        float* C = lin + (size_t)b * Nn * 256;
#pragma unroll
        for (int reg = 0; reg < 16; ++reg) {
            int rl = 4 * kh + (reg & 3) + 8 * (reg >> 2);
            C[(size_t)(m0 + rl) * 256 + colg] = acc[reg];
        }
    } else {
        unsigned short* CF = h2f + (size_t)b * 524288;
#pragma unroll
        for (int q = 0; q < 4; ++q) {
            int kt = m0 / 16 + (q >> 1);
            size_t fi = ((size_t)(colg >> 5) * 128 + kt) * 512 +
                        ((q & 1) * 32 + (colg & 31)) * 8 + kh * 4;
            ushort4_t pk;
            pk.x = f2bf(acc[q * 4 + 0]);
            pk.y = f2bf(acc[q * 4 + 1]);
            pk.z = f2bf(acc[q * 4 + 2]);
            pk.w = f2bf(acc[q * 4 + 3]);
            *(ushort4_t*)(CF + fi) = pk;
        }
        float a1v = a_out[colg];
        float a2v = a_out[256 + colg];
        float* sbuf = (float*)As;
#pragma unroll
        for (int reg = 0; reg < 16; ++reg) {
            int rl = 4 * kh + (reg & 3) + 8 * (reg >> 2);
            float v1 = acc[reg] * a1v;
            float v2 = acc[reg] * a2v;
#pragma unroll
            for (int m = 1; m <= 16; m <<= 1) {
                v1 += __shfl_xor(v1, m, 64);
                v2 += __shfl_xor(v2, m, 64);
            }
            if (lm == 0) { sbuf[rl * 16 + wv] = v1; sbuf[rl * 16 + 8 + wv] = v2; }
        }
        __syncthreads();
        if (t < 32) {
            float s1 = 0.f, s2 = 0.f;
#pragma unroll
            for (int k = 0; k < 8; ++k) {
                s1 += sbuf[t * 16 + k];
                s2 += sbuf[t * 16 + 8 + k];
            }
            size_t ei = (size_t)b * Nn + m0 + t;
            E1p[ei] = __expf(s1);
            E1n[ei] = __expf(0.2f * s1);
            E2pn[ei] = make_float2(__expf(s2), __expf(0.2f * s2));
        }
    }
}

// ---------------- final GEMM with fused combine, BK=128, o-split x2 ----------------
__global__ __launch_bounds__(256) void gemm32_final_kernel(
        const float* __restrict__ pacc, const float* __restrict__ plsum,
        const float* __restrict__ lin, const float* __restrict__ b_lin,
        const unsigned short* __restrict__ BF, const float* __restrict__ b_ln,
        float* __restrict__ out) {
    int b = blockIdx.z, oc = blockIdx.y;
    int m0 = blockIdx.x * 32;
    int t = threadIdx.x;
    int wv = t >> 6, lane = t & 63;
    int lm = lane & 31, kh = lane >> 5;
    constexpr int nfk = 16;   // K = 256
    __shared__ __align__(16) unsigned short As[32][136];
    f32x16 acc = {};
    int sr = t >> 3, sc2 = (t & 7) * 16;
    int row = m0 + sr;
    int BN = Bb * Nn;
    size_t prow = (size_t)b * Nn + row;
    float li = 1.f / (plsum[prow] + plsum[prow + BN] + plsum[prow + 2 * BN] + plsum[prow + 3 * BN]);
    size_t ps4 = (size_t)Bb * Nn * 256;
    const unsigned short* bg = BF + (size_t)(oc * 4 + wv) * nfk * 512;
    for (int k0 = 0; k0 < 256; k0 += 128) {
        int o = k0 + sc2;
        size_t pidx = prow * 256 + o;
#pragma unroll
        for (int g = 0; g < 4; ++g) {
            float4 s4 = *(const float4*)(pacc + pidx + 4 * g);
#pragma unroll
            for (int k = 1; k < 4; ++k) {
                float4 q = *(const float4*)(pacc + k * ps4 + pidx + 4 * g);
                s4.x += q.x; s4.y += q.y; s4.z += q.z; s4.w += q.w;
            }
            float4 lv = *(const float4*)(lin + pidx + 4 * g);
            float4 bv = *(const float4*)(b_lin + o + 4 * g);
            ushort4_t pk;
            pk.x = f2bf(s4.x * li + lv.x + bv.x);
            pk.y = f2bf(s4.y * li + lv.y + bv.y);
            pk.z = f2bf(s4.z * li + lv.z + bv.z);
            pk.w = f2bf(s4.w * li + lv.w + bv.w);
            *(ushort4_t*)&As[sr][sc2 + 4 * g] = pk;
        }
        int kt0 = k0 >> 4;
        __syncthreads();
#pragma unroll
        for (int s = 0; s < 8; ++s) {
            short8 a0 = *(const short8*)&As[lm][s * 16 + kh * 8];
            short8 b0 = *(const short8*)(bg + (size_t)(kt0 + s) * 512 + lane * 8);
            acc = __builtin_amdgcn_mfma_f32_32x32x16_bf16(a0, b0, acc, 0, 0, 0);
        }
        __syncthreads();
    }
    float* C = out + (size_t)b * Nn * 256;
    int colg = oc * 128 + wv * 32 + lm;
    float bv = b_ln[colg];
#pragma unroll
    for (int reg = 0; reg < 16; ++reg) {
        int rl = 4 * kh + (reg & 3) + 8 * (reg >> 2);
        float v = fmaxf(acc[reg] + bv, 0.f);
        C[(size_t)(m0 + rl) * 256 + colg] = v;
    }
}

// ---------------- attention 32-row (R1-verified v9: 4-slot rotation + setprio) ----------------
template<int JLEN, int MODE, int SWAPXY>
__global__ __launch_bounds__(256, 4) void attn32_kernel(
        const unsigned short* __restrict__ hfrag,
        const unsigned* __restrict__ bits,
        const float* __restrict__ E1p, const float* __restrict__ E1n,
        const float2* __restrict__ E2pn,
        unsigned short* __restrict__ outbf, int ldo,
        float* __restrict__ pacc, float* __restrict__ plsum,
        int hshift) {
    constexpr int W = JLEN / 32, NC = JLEN / 64, ABS = W + 1;
    int it = SWAPXY ? blockIdx.y : blockIdx.x;
    int bh = SWAPXY ? blockIdx.x : blockIdx.y;
    int js = blockIdx.z;
    int b = bh >> hshift, hd = bh & ((1 << hshift) - 1);
    int i0 = it * 32, jbase = js * JLEN;
    int kt0 = js * (JLEN / 16);
    int t = threadIdx.x, lane = t & 63;
    int wv = t >> 6, lm = lane & 31, kh = lane >> 5;
    int ti = t & 31, jq = t >> 5;

    __shared__ unsigned ab[32 * ABS];
    __shared__ __align__(16) unsigned short ps[2][32][64];
    __shared__ float lred[32][9];
    __shared__ float linv[32];

    const unsigned* bb = bits + ((size_t)b * Nn + i0) * 64 + (jbase >> 5);
    for (int k = t; k < 32 * W; k += 256) {
        int r = k / W, w0 = k - r * W;
        ab[r * ABS + w0] = bb[(size_t)r * 64 + w0];
    }
    __syncthreads();

    float e1p = E1p[(size_t)bh * Nn + i0 + ti];
    float e1n = E1n[(size_t)bh * Nn + i0 + ti];
    const float4* e2base = (const float4*)(E2pn + (size_t)bh * Nn + jbase);

    const unsigned short* bg0 = hfrag + (size_t)bh * 524288 + (size_t)(wv * 2) * 128 * 512;
    const unsigned short* bg1 = bg0 + 128 * 512;

    f32x16 acc[2] = {};
    float lp0 = 0.f, lp1 = 0.f;
    short8 Bpp[4][2];

    auto loadBs = [&](int c, int s, int slot) {
        int kt = kt0 + c * 4 + s;
        Bpp[slot][0] = *(const short8*)(bg0 + (size_t)kt * 512 + lane * 8);
        Bpp[slot][1] = *(const short8*)(bg1 + (size_t)kt * 512 + lane * 8);
    };
    auto computeP = [&](int c, int buf) {
        int cj = c * 64;
        unsigned word = ab[ti * ABS + (cj >> 5) + (jq >> 2)];
        unsigned field = (word >> ((jq & 3) * 8)) & 0xffu;
        const float4* ep = e2base + ((cj + jq * 8) >> 1);
        unsigned pk[4];
#pragma unroll
        for (int u = 0; u < 4; ++u) {
            float4 q = ep[u];
            float p0 = fmaxf(e1p * q.x, e1n * q.y);
            p0 = ((field >> (2 * u)) & 1u) ? p0 : 0.f;
            float p1 = fmaxf(e1p * q.z, e1n * q.w);
            p1 = ((field >> (2 * u + 1)) & 1u) ? p1 : 0.f;
            if (u & 1) lp1 += p0 + p1; else lp0 += p0 + p1;
            __hip_bfloat162 hv = __float22bfloat162_rn(make_float2(p0, p1));
            pk[u] = *(unsigned*)&hv;
        }
        uint4 v; v.x = pk[0]; v.y = pk[1]; v.z = pk[2]; v.w = pk[3];
        *(uint4*)&ps[buf][ti][(jq ^ (ti & 7)) * 8] = v;
    };
    auto mfmaS = [&](int buf, int s, int slot) {
        int g = 2 * s + kh;
        short8 a0 = *(const short8*)&ps[buf][lm][(g ^ (lm & 7)) * 8];
        __builtin_amdgcn_s_setprio(1);
        acc[0] = __builtin_amdgcn_mfma_f32_32x32x16_bf16(a0, Bpp[slot][0], acc[0], 0, 0, 0);
        acc[1] = __builtin_amdgcn_mfma_f32_32x32x16_bf16(a0, Bpp[slot][1], acc[1], 0, 0, 0);
        __builtin_amdgcn_s_setprio(0);
    };

    computeP(0, 0);
    loadBs(0, 0, 0); loadBs(0, 1, 1); loadBs(0, 2, 2); loadBs(0, 3, 3);
    __syncthreads();
    for (int c = 0; c + 1 < NC; ++c) {
        int cb = c & 1, nb = cb ^ 1;
        computeP(c + 1, nb);
        mfmaS(cb, 0, 0);  loadBs(c + 1, 0, 0);
        mfmaS(cb, 1, 1);  loadBs(c + 1, 1, 1);
        mfmaS(cb, 2, 2);  loadBs(c + 1, 2, 2);
        mfmaS(cb, 3, 3);  loadBs(c + 1, 3, 3);
        __syncthreads();
    }
    {
        int cb = (NC - 1) & 1;
        mfmaS(cb, 0, 0);
        mfmaS(cb, 1, 1);
        mfmaS(cb, 2, 2);
        mfmaS(cb, 3, 3);
    }

    lred[ti][jq] = lp0 + lp1;
    __syncthreads();
    if (MODE == 0) {
        if (t < 32) {
            float s = 0.f;
#pragma unroll
            for (int k = 0; k < 8; ++k) s += lred[t][k];
            linv[t] = 1.f / s;
        }
        __syncthreads();
#pragma unroll
        for (int nt = 0; nt < 2; ++nt) {
            int o = wv * 64 + nt * 32 + lm;
#pragma unroll
            for (int reg = 0; reg < 16; ++reg) {
                int rl = 4 * kh + (reg & 3) + 8 * (reg >> 2);
                float v = acc[nt][reg] * linv[rl];
                v = v > 0.f ? v : expm1f(v);
                outbf[((size_t)b * Nn + i0 + rl) * ldo + (size_t)hd * Oo + o] = f2bf(v);
            }
        }
    } else {
        if (t < 32) {
            float s = 0.f;
#pragma unroll
            for (int k = 0; k < 8; ++k) s += lred[t][k];
            plsum[((size_t)js * Bb + b) * Nn + i0 + t] = s;
        }
        float* pa = pacc + (((size_t)js * Bb + b) * Nn) * 256;
#pragma unroll
        for (int nt = 0; nt < 2; ++nt) {
            int o = wv * 64 + nt * 32 + lm;
#pragma unroll
            for (int reg = 0; reg < 16; ++reg) {
                int rl = 4 * kh + (reg & 3) + 8 * (reg >> 2);
                pa[(size_t)(i0 + rl) * 256 + o] = acc[nt][reg];
            }
        }
    }
}

// ---------------- attention 64-row: 2-deep e2 prefetch, STATIC buffer naming ----------------
// Rule-#20-safe rewrite of R10: the main loop is hand-unrolled x2 so every e2a/e2b use is
// a compile-time-fixed name (even chunks in e2a, odd in e2b); ps buffers are literals.
// Chunk c+2's e2 load issues at the top of phase c; computeP consumes it one phase later.
template<int JLEN, int MODE, int SWAPXY>
__global__ __launch_bounds__(256, 2) void attn64_kernel(
        const unsigned short* __restrict__ hfrag,
        const unsigned* __restrict__ bits,
        const float* __restrict__ E1p, const float* __restrict__ E1n,
        const float2* __restrict__ E2pn,
        unsigned short* __restrict__ outbf, int ldo,
        float* __restrict__ pacc, float* __restrict__ plsum,
        int hshift) {
    constexpr int W = JLEN / 32, NC = JLEN / 64, ABS = W + 1;
    static_assert(NC >= 4 && (NC & 1) == 0, "pair-unrolled loop needs even NC >= 4");
    int it = SWAPXY ? blockIdx.y : blockIdx.x;
    int bh = SWAPXY ? blockIdx.x : blockIdx.y;
    int js = blockIdx.z;
    int b = bh >> hshift, hd = bh & ((1 << hshift) - 1);
    int i0 = it * 64, jbase = js * JLEN;
    int kt0 = js * (JLEN / 16);
    int t = threadIdx.x, lane = t & 63;
    int wv = t >> 6, lm = lane & 31, kh = lane >> 5;
    int ti = t & 31, jq = t >> 5;

    __shared__ unsigned ab[64 * ABS];
    __shared__ __align__(16) unsigned short ps[2][64][64];
    __shared__ float lred[64][9];
    __shared__ float linv[64];

    const unsigned* bb = bits + ((size_t)b * Nn + i0) * 64 + (jbase >> 5);
    for (int k = t; k < 64 * W; k += 256) {
        int r = k / W, w0 = k - r * W;
        ab[r * ABS + w0] = bb[(size_t)r * 64 + w0];
    }
    __syncthreads();

    float e1pA = E1p[(size_t)bh * Nn + i0 + ti];
    float e1nA = E1n[(size_t)bh * Nn + i0 + ti];
    float e1pB = E1p[(size_t)bh * Nn + i0 + 32 + ti];
    float e1nB = E1n[(size_t)bh * Nn + i0 + 32 + ti];
    const float4* e2base = (const float4*)(E2pn + (size_t)bh * Nn + jbase);

    const unsigned short* bg0 = hfrag + (size_t)bh * 524288 + (size_t)(wv * 2) * 128 * 512;
    const unsigned short* bg1 = bg0 + 128 * 512;

    f32x16 acc[4] = {};
    float lpA = 0.f, lpB = 0.f;
    short8 Bpp[4][2];
    float4 e2a[4], e2b[4];   // even chunks -> e2a, odd -> e2b (all uses statically named)

    auto loadE2 = [&](int c, float4 (&e2)[4]) {
        const float4* ep = e2base + ((c * 64 + jq * 8) >> 1);
#pragma unroll
        for (int u = 0; u < 4; ++u) e2[u] = ep[u];
    };
    auto loadBs = [&](int c, int s, int slot) {
        int kt = kt0 + c * 4 + s;
        Bpp[slot][0] = *(const short8*)(bg0 + (size_t)kt * 512 + lane * 8);
        Bpp[slot][1] = *(const short8*)(bg1 + (size_t)kt * 512 + lane * 8);
    };
    auto computeP = [&](int c, int buf, const float4 (&e2)[4]) {
        int cj = c * 64;
        int wi = (cj >> 5) + (jq >> 2);
        unsigned wordA = ab[ti * ABS + wi];
        unsigned wordB = ab[(ti + 32) * ABS + wi];
        unsigned fieldA = (wordA >> ((jq & 3) * 8)) & 0xffu;
        unsigned fieldB = (wordB >> ((jq & 3) * 8)) & 0xffu;
        unsigned pkA[4], pkB[4];
#pragma unroll
        for (int u = 0; u < 4; ++u) {
            float4 q = e2[u];   // preloaded one full phase ago
            float a0v = fmaxf(e1pA * q.x, e1nA * q.y);
            a0v = ((fieldA >> (2 * u)) & 1u) ? a0v : 0.f;
            float a1v = fmaxf(e1pA * q.z, e1nA * q.w);
            a1v = ((fieldA >> (2 * u + 1)) & 1u) ? a1v : 0.f;
            lpA += a0v + a1v;
            float b0v = fmaxf(e1pB * q.x, e1nB * q.y);
            b0v = ((fieldB >> (2 * u)) & 1u) ? b0v : 0.f;
            float b1v = fmaxf(e1pB * q.z, e1nB * q.w);
            b1v = ((fieldB >> (2 * u + 1)) & 1u) ? b1v : 0.f;
            lpB += b0v + b1v;
            __hip_bfloat162 hA = __float22bfloat162_rn(make_float2(a0v, a1v));
            __hip_bfloat162 hB = __float22bfloat162_rn(make_float2(b0v, b1v));
            pkA[u] = *(unsigned*)&hA;
            pkB[u] = *(unsigned*)&hB;
        }
        int col = (jq ^ (ti & 7)) * 8;
        uint4 vA; vA.x = pkA[0]; vA.y = pkA[1]; vA.z = pkA[2]; vA.w = pkA[3];
        uint4 vB; vB.x = pkB[0]; vB.y = pkB[1]; vB.z = pkB[2]; vB.w = pkB[3];
        *(uint4*)&ps[buf][ti][col] = vA;
        *(uint4*)&ps[buf][ti + 32][col] = vB;
    };
    auto mfmaS = [&](int buf, int s, int slot) {
        int g = 2 * s + kh;
        int col = (g ^ (lm & 7)) * 8;
        short8 a0 = *(const short8*)&ps[buf][lm][col];
        short8 a1 = *(const short8*)&ps[buf][32 + lm][col];
        __builtin_amdgcn_s_setprio(1);
        acc[0] = __builtin_amdgcn_mfma_f32_32x32x16_bf16(a0, Bpp[slot][0], acc[0], 0, 0, 0);
        acc[1] = __builtin_amdgcn_mfma_f32_32x32x16_bf16(a0, Bpp[slot][1], acc[1], 0, 0, 0);
        acc[2] = __builtin_amdgcn_mfma_f32_32x32x16_bf16(a1, Bpp[slot][0], acc[2], 0, 0, 0);
        acc[3] = __builtin_amdgcn_mfma_f32_32x32x16_bf16(a1, Bpp[slot][1], acc[3], 0, 0, 0);
        __builtin_amdgcn_s_setprio(0);
    };

    // prologue: chunk 0 -> e2a, chunk 1 -> e2b; P(0) into ps[0]; B slots hold chunk 0
    loadE2(0, e2a);
    loadE2(1, e2b);
    computeP(0, 0, e2a);
    loadBs(0, 0, 0); loadBs(0, 1, 1); loadBs(0, 2, 2); loadBs(0, 3, 3);
    __syncthreads();

    for (int c = 0; c + 3 < NC; c += 2) {
        // even phase: MFMA chunk c (ps[0]); P(c+1) from e2b into ps[1]; e2a <- chunk c+2
        loadE2(c + 2, e2a);
        computeP(c + 1, 1, e2b);
        mfmaS(0, 0, 0);  loadBs(c + 1, 0, 0);
        mfmaS(0, 1, 1);  loadBs(c + 1, 1, 1);
        mfmaS(0, 2, 2);  loadBs(c + 1, 2, 2);
        mfmaS(0, 3, 3);  loadBs(c + 1, 3, 3);
        __syncthreads();
        // odd phase: MFMA chunk c+1 (ps[1]); P(c+2) from e2a into ps[0]; e2b <- chunk c+3
        loadE2(c + 3, e2b);
        computeP(c + 2, 0, e2a);
        mfmaS(1, 0, 0);  loadBs(c + 2, 0, 0);
        mfmaS(1, 1, 1);  loadBs(c + 2, 1, 1);
        mfmaS(1, 2, 2);  loadBs(c + 2, 2, 2);
        mfmaS(1, 3, 3);  loadBs(c + 2, 3, 3);
        __syncthreads();
    }
    // tail: c = NC-2 — MFMA chunk NC-2 (ps[0]); P(NC-1) from e2b into ps[1]
    computeP(NC - 1, 1, e2b);
    mfmaS(0, 0, 0);  loadBs(NC - 1, 0, 0);
    mfmaS(0, 1, 1);  loadBs(NC - 1, 1, 1);
    mfmaS(0, 2, 2);  loadBs(NC - 1, 2, 2);
    mfmaS(0, 3, 3);  loadBs(NC - 1, 3, 3);
    __syncthreads();
    // epilogue: MFMA chunk NC-1 (ps[1])
    mfmaS(1, 0, 0);
    mfmaS(1, 1, 1);
    mfmaS(1, 2, 2);
    mfmaS(1, 3, 3);

    lred[ti][jq] = lpA;
    lred[ti + 32][jq] = lpB;
    __syncthreads();
    if (MODE == 0) {
        if (t < 64) {
            float s = 0.f;
#pragma unroll
            for (int k = 0; k < 8; ++k) s += lred[t][k];
            linv[t] = 1.f / s;
        }
        __syncthreads();
#pragma unroll
        for (int ih = 0; ih < 2; ++ih) {
#pragma unroll
            for (int nt = 0; nt < 2; ++nt) {
                int o = wv * 64 + nt * 32 + lm;
#pragma unroll
                for (int reg = 0; reg < 16; ++reg) {
                    int rl = 4 * kh + (reg & 3) + 8 * (reg >> 2);
                    int row = ih * 32 + rl;
                    float v = acc[ih * 2 + nt][reg] * linv[row];
                    v = v > 0.f ? v : expm1f(v);
                    outbf[((size_t)b * Nn + i0 + row) * ldo + (size_t)hd * Oo + o] = f2bf(v);
                }
            }
        }
    } else {
        if (t < 64) {
            float s = 0.f;
#pragma unroll
            for (int k = 0; k < 8; ++k) s += lred[t][k];
            plsum[((size_t)js * Bb + b) * Nn + i0 + t] = s;
        }
        float* pa = pacc + (((size_t)js * Bb + b) * Nn) * 256;
#pragma unroll
        for (int ih = 0; ih < 2; ++ih) {
#pragma unroll
            for (int nt = 0; nt < 2; ++nt) {
                int o = wv * 64 + nt * 32 + lm;
#pragma unroll
                for (int reg = 0; reg < 16; ++reg) {
                    int rl = 4 * kh + (reg & 3) + 8 * (reg >> 2);
                    int row = ih * 32 + rl;
                    pa[(size_t)(i0 + row) * 256 + o] = acc[ih * 2 + nt][reg];
                }
            }
        }
    }
}

extern "C" void kernel_launch(void* const* d_in, const int* in_sizes, int n_in,
                              void* d_out, int out_size, void* d_ws, size_t ws_size,
                              hipStream_t stream) {
    const float* x       = (const float*)d_in[0];
    const float* adj     = (const float*)d_in[1];
    const float* W_heads = (const float*)d_in[3];
    const float* a_heads = (const float*)d_in[4];
    const float* W_out   = (const float*)d_in[5];
    const float* a_out   = (const float*)d_in[6];
    const float* W_lin   = (const float*)d_in[7];
    const float* b_lin   = (const float*)d_in[8];
    const float* W_ln    = (const float*)d_in[9];
    const float* b_ln    = (const float*)d_in[10];

    char* w = (char*)d_ws;
    float* pacc     = (float*)(w);                    // 4x4 MB (sh partials)
    float* lin      = (float*)(w + 33554432);
    float* E1p_mh   = (float*)(w + 41943040);
    float* E1n_mh   = (float*)(w + 42074112);
    float2* E2pn_mh = (float2*)(w + 42205184);
    float* E1p_sh   = (float*)(w + 42467328);
    float* E1n_sh   = (float*)(w + 42483712);
    float2* E2pn_sh = (float2*)(w + 42500096);
    unsigned long long* bits = (unsigned long long*)(w + 42532864);
    unsigned short* x_bf  = (unsigned short*)(w + 43581440);
    unsigned short* WhF   = (unsigned short*)(w + 49872896);
    unsigned short* WoF   = (unsigned short*)(w + 53018624);
    unsigned short* WlF   = (unsigned short*)(w + 54067200);
    unsigned short* WnF   = (unsigned short*)(w + 55115776);
    unsigned short* hfrag = (unsigned short*)(w + 55246848);   // 16 MB
    unsigned short* h2frag= (unsigned short*)(w + 72024064);   // 2 MB
    unsigned short* x1_bf = (unsigned short*)(w + 74121216);
    float* plsum = E1p_mh;

    // 0) merged prep: adjbits + x cast + all weight frags (1 launch)
    prep_misc_kernel<<<37152, 256, 0, stream>>>(
        adj, bits, x, x_bf, W_heads, WhF, W_out, WoF, W_lin, WlF, W_ln, WnF);

    // 1) h = x @ W_heads -> hfrag + fused mh scores/exp (z-major: XCD = z%8)
    gemm32_kernel<1><<<dim3(Bb * Hh, Nn / 32, 1), 256, 0, stream>>>(
        x_bf, Ff, (long long)Nn * Ff, 3, WhF, 384LL * 512, 7,
        nullptr, 0, hfrag, 524288, Nn, nullptr, 1,
        a_heads, 7, E1p_mh, E1n_mh, E2pn_mh);
    // 2) multihead attention + elu -> x1_bf  (64-row tiles + static 2-deep e2 prefetch)
    attn64_kernel<2048, 0, 1><<<dim3(Bb * Hh, Nn / 64, 1), 256, 0, stream>>>(
        hfrag, (const unsigned*)bits, E1p_mh, E1n_mh, E2pn_mh,
        x1_bf, Hh * Oo, nullptr, nullptr, 3);
    // 3) fused dual GEMM: h2frag (+sh scores) and lin — 8-wave blocks
    gemm32_dual_kernel<<<dim3(Nn / 32, 2, Bb), 512, 0, stream>>>(
        x1_bf, Hh * Oo, (long long)Nn * Hh * Oo, WoF, h2frag, lin,
        a_out, E1p_sh, E1n_sh, E2pn_sh);
    // 4) single-head attention, 4-way j-split partials (32-row, 2 blocks/CU)
    attn32_kernel<512, 1, 0><<<dim3(Nn / 32, Bb, 4), 256, 0, stream>>>(
        h2frag, (const unsigned*)bits, E1p_sh, E1n_sh, E2pn_sh,
        nullptr, 0, pacc, plsum, 0);
    // 5) final GEMM with fused combine (o-split x2) -> d_out
    gemm32_final_kernel<<<dim3(Nn / 32, 2, Bb), 256, 0, stream>>>(
        pacc, plsum, lin, b_lin, WnF, b_ln, (float*)d_out);
}

// Round 12
// 236.263 us; speedup vs baseline: 1.3294x; 1.0050x over previous
//
#include <hip/hip_runtime.h>
#include <hip/hip_bf16.h>

constexpr int Bb = 2, Nn = 2048, Ff = 768, Hh = 8, Oo = 256;

typedef __attribute__((ext_vector_type(8)))  short   short8;
typedef __attribute__((ext_vector_type(16))) float   f32x16;
typedef __attribute__((ext_vector_type(4)))  unsigned short ushort4_t;

__device__ inline unsigned short f2bf(float f) {
    unsigned u = __float_as_uint(f);
    u = (u + 0x7FFFu + ((u >> 16) & 1u)) >> 16;   // RNE
    return (unsigned short)u;
}

// ======== B-fragment layout: frag id = nt32*(K/16)+kt, 1 KB each ========
__device__ inline void wfrag_kn_body(
        const float* __restrict__ W, unsigned short* __restrict__ out,
        int K, int N, int fblk, int t) {
    int f = fblk * 4 + (t >> 6);
    int slot = t & 63, kh = slot >> 5, lm = slot & 31;
    int nfk = K >> 4;
    int nt = f / nfk, kt = f - nt * nfk;
    const float* wp = W + (size_t)(kt * 16 + kh * 8) * N + nt * 32 + lm;
    ushort4_t o0, o1;
    o0.x = f2bf(wp[0]);             o0.y = f2bf(wp[(size_t)N]);
    o0.z = f2bf(wp[2 * (size_t)N]); o0.w = f2bf(wp[3 * (size_t)N]);
    o1.x = f2bf(wp[4 * (size_t)N]); o1.y = f2bf(wp[5 * (size_t)N]);
    o1.z = f2bf(wp[6 * (size_t)N]); o1.w = f2bf(wp[7 * (size_t)N]);
    unsigned short* op = out + (size_t)f * 512 + slot * 8;
    *(ushort4_t*)op = o0;
    *(ushort4_t*)(op + 4) = o1;
}

__device__ inline void wfrag_nk_body(
        const float* __restrict__ W, unsigned short* __restrict__ out,
        int K, int fblk, int t) {
    int f = fblk * 4 + (t >> 6);
    int slot = t & 63, kh = slot >> 5, lm = slot & 31;
    int nfk = K >> 4;
    int nt = f / nfk, kt = f - nt * nfk;
    const float* wp = W + (size_t)(nt * 32 + lm) * K + kt * 16 + kh * 8;
    float4 a = *(const float4*)wp, b = *(const float4*)(wp + 4);
    ushort4_t o0, o1;
    o0.x = f2bf(a.x); o0.y = f2bf(a.y); o0.z = f2bf(a.z); o0.w = f2bf(a.w);
    o1.x = f2bf(b.x); o1.y = f2bf(b.y); o1.z = f2bf(b.z); o1.w = f2bf(b.w);
    unsigned short* op = out + (size_t)f * 512 + slot * 8;
    *(ushort4_t*)op = o0;
    *(ushort4_t*)(op + 4) = o1;
}

// ---------------- merged prep: adjbits + x cast + all weight frag tables (1 launch) ----------------
__global__ __launch_bounds__(256) void prep_misc_kernel(
        const float* __restrict__ adj, unsigned long long* __restrict__ bits,
        const float* __restrict__ x, unsigned short* __restrict__ x_bf,
        const float* __restrict__ W_heads, unsigned short* __restrict__ WhF,
        const float* __restrict__ W_out,   unsigned short* __restrict__ WoF,
        const float* __restrict__ W_lin,   unsigned short* __restrict__ WlF,
        const float* __restrict__ W_ln,    unsigned short* __restrict__ WnF) {
    int blk = blockIdx.x, t = threadIdx.x;
    if (blk < 32768) {
        size_t gid = (size_t)blk * 256 + t;
        float v = adj[gid];
        unsigned long long m = __ballot(v > 0.f);
        if ((t & 63) == 0) bits[gid >> 6] = m;
    } else if (blk < 35840) {
        size_t i = (size_t)(blk - 32768) * 256 + t;
        float4 v = ((const float4*)x)[i];
        ushort4_t o;
        o.x = f2bf(v.x); o.y = f2bf(v.y); o.z = f2bf(v.z); o.w = f2bf(v.w);
        ((ushort4_t*)x_bf)[i] = o;
    } else if (blk < 36608) {
        int idx = blk - 35840;
        int head = idx / 96, fblk = idx - head * 96;
        wfrag_kn_body(W_heads + (size_t)head * Ff * Oo, WhF + (size_t)head * 384 * 512,
                      Ff, Oo, fblk, t);
    } else if (blk < 36864) {
        wfrag_kn_body(W_out, WoF, Hh * Oo, Oo, blk - 36608, t);
    } else if (blk < 37120) {
        wfrag_nk_body(W_lin, WlF, Hh * Oo, blk - 36864, t);
    } else {
        wfrag_nk_body(W_ln, WnF, Oo, blk - 37120, t);
    }
}

// ---------------- 32-row-tile MFMA GEMM, BK=128 (R18 verified) ----------------
template<int SWAPZ>
__global__ __launch_bounds__(256) void gemm32_kernel(
        const unsigned short* __restrict__ A, int K, long long sA, int bAshift,
        const unsigned short* __restrict__ BF, long long sB, int bmask,
        float* __restrict__ C, long long sC,
        unsigned short* __restrict__ CF, long long sCF, int Mtot,
        const float* __restrict__ bias, int mode,
        const float* __restrict__ aall, int amask,
        float* __restrict__ E1p, float* __restrict__ E1n, float2* __restrict__ E2pn) {
    int z  = SWAPZ ? blockIdx.x : blockIdx.z;
    int mx = SWAPZ ? blockIdx.y : blockIdx.x;
    A  += (size_t)(z >> bAshift) * sA;
    BF += (size_t)(z & bmask) * sB;
    if (C) C += (size_t)z * sC;
    if (CF) CF += (size_t)z * sCF;
    int m0 = mx * 32;
    int t = threadIdx.x;
    int wv = t >> 6, lane = t & 63;
    int lm = lane & 31, kh = lane >> 5;
    int nfk = K >> 4;
    __shared__ __align__(16) unsigned short As[32][136];
    f32x16 acc[2] = {};
    int sr = t >> 3, sc2 = (t & 7) * 16;
    const unsigned short* ag  = A + (size_t)(m0 + sr) * K + sc2;
    const unsigned short* bg0 = BF + (size_t)(wv * 2) * nfk * 512;
    const unsigned short* bg1 = bg0 + (size_t)nfk * 512;
    for (int k0 = 0; k0 < K; k0 += 128) {
        *(short8*)&As[sr][sc2]     = *(const short8*)(ag + k0);
        *(short8*)&As[sr][sc2 + 8] = *(const short8*)(ag + k0 + 8);
        int kt0 = k0 >> 4;
        __syncthreads();
#pragma unroll
        for (int s = 0; s < 8; ++s) {
            short8 a0 = *(const short8*)&As[lm][s * 16 + kh * 8];
            short8 b0 = *(const short8*)(bg0 + (size_t)(kt0 + s) * 512 + lane * 8);
            short8 b1 = *(const short8*)(bg1 + (size_t)(kt0 + s) * 512 + lane * 8);
            acc[0] = __builtin_amdgcn_mfma_f32_32x32x16_bf16(a0, b0, acc[0], 0, 0, 0);
            acc[1] = __builtin_amdgcn_mfma_f32_32x32x16_bf16(a0, b1, acc[1], 0, 0, 0);
        }
        __syncthreads();
    }
#pragma unroll
    for (int nt = 0; nt < 2; ++nt) {
        int colg = wv * 64 + nt * 32 + lm;
        float bv = (mode == 2) ? bias[colg] : 0.f;
        if (C) {
#pragma unroll
            for (int reg = 0; reg < 16; ++reg) {
                int rl = 4 * kh + (reg & 3) + 8 * (reg >> 2);
                float v = acc[nt][reg];
                if (mode == 2) { v += bv; v = fmaxf(v, 0.f); }
                C[(size_t)(m0 + rl) * 256 + colg] = v;
            }
        }
        if (mode == 1) {
#pragma unroll
            for (int q = 0; q < 4; ++q) {
                int kt = m0 / 16 + (q >> 1);
                size_t fi = ((size_t)(colg >> 5) * (Mtot / 16) + kt) * 512 +
                            ((q & 1) * 32 + (colg & 31)) * 8 + kh * 4;
                ushort4_t pk;
                pk.x = f2bf(acc[nt][q * 4 + 0]);
                pk.y = f2bf(acc[nt][q * 4 + 1]);
                pk.z = f2bf(acc[nt][q * 4 + 2]);
                pk.w = f2bf(acc[nt][q * 4 + 3]);
                *(ushort4_t*)(CF + fi) = pk;
            }
        }
    }
    if (aall) {
        const float* av = aall + (size_t)(z & amask) * 512;
        float a1v0 = av[wv * 64 + lm],       a1v1 = av[wv * 64 + 32 + lm];
        float a2v0 = av[256 + wv * 64 + lm], a2v1 = av[256 + wv * 64 + 32 + lm];
        float* sbuf = (float*)As;
#pragma unroll
        for (int reg = 0; reg < 16; ++reg) {
            int rl = 4 * kh + (reg & 3) + 8 * (reg >> 2);
            float v1 = acc[0][reg] * a1v0 + acc[1][reg] * a1v1;
            float v2 = acc[0][reg] * a2v0 + acc[1][reg] * a2v1;
#pragma unroll
            for (int m = 1; m <= 16; m <<= 1) {
                v1 += __shfl_xor(v1, m, 64);
                v2 += __shfl_xor(v2, m, 64);
            }
            if (lm == 0) { sbuf[rl * 8 + wv] = v1; sbuf[rl * 8 + 4 + wv] = v2; }
        }
        __syncthreads();
        if (t < 32) {
            float s1 = sbuf[t * 8] + sbuf[t * 8 + 1] + sbuf[t * 8 + 2] + sbuf[t * 8 + 3];
            float s2 = sbuf[t * 8 + 4] + sbuf[t * 8 + 5] + sbuf[t * 8 + 6] + sbuf[t * 8 + 7];
            size_t ei = (size_t)z * Nn + m0 + t;
            E1p[ei] = __expf(s1);
            E1n[ei] = __expf(0.2f * s1);
            E2pn[ei] = make_float2(__expf(s2), __expf(0.2f * s2));
        }
    }
}

// ---------------- 32-row dual GEMM, BK=128 — 8-wave blocks (2 waves/SIMD) ----------------
__global__ __launch_bounds__(512) void gemm32_dual_kernel(
        const unsigned short* __restrict__ A, int K, long long sA,
        const unsigned short* __restrict__ BF,
        unsigned short* __restrict__ h2f, float* __restrict__ lin,
        const float* __restrict__ a_out,
        float* __restrict__ E1p, float* __restrict__ E1n, float2* __restrict__ E2pn) {
    int b = blockIdx.z, ng = blockIdx.y;
    A += (size_t)b * sA;
    int nfk = K >> 4;
    BF += (size_t)ng * 8 * nfk * 512;
    int m0 = blockIdx.x * 32;
    int t = threadIdx.x;
    int wv = t >> 6, lane = t & 63;          // wv in 0..7
    int lm = lane & 31, kh = lane >> 5;
    __shared__ __align__(16) unsigned short As[32][136];
    f32x16 acc = {};
    int sr = t >> 4, sc2 = (t & 15) * 8;     // 512 threads: one short8 each
    const unsigned short* ag = A + (size_t)(m0 + sr) * K + sc2;
    const unsigned short* bg = BF + (size_t)wv * nfk * 512;
    for (int k0 = 0; k0 < K; k0 += 128) {
        *(short8*)&As[sr][sc2] = *(const short8*)(ag + k0);
        int kt0 = k0 >> 4;
        __syncthreads();
#pragma unroll
        for (int s = 0; s < 8; ++s) {
            short8 a0 = *(const short8*)&As[lm][s * 16 + kh * 8];
            short8 b0 = *(const short8*)(bg + (size_t)(kt0 + s) * 512 + lane * 8);
            acc = __builtin_amdgcn_mfma_f32_32x32x16_bf16(a0, b0, acc, 0, 0, 0);
        }
        __syncthreads();
    }
    int colg = wv * 32 + lm;
    if (ng == 1) {
        float* C = lin + (size_t)b * Nn * 256;
#pragma unroll
        for (int reg = 0; reg < 16; ++reg) {
            int rl = 4 * kh + (reg & 3) + 8 * (reg >> 2);
            C[(size_t)(m0 + rl) * 256 + colg] = acc[reg];
        }
    } else {
        unsigned short* CF = h2f + (size_t)b * 524288;
#pragma unroll
        for (int q = 0; q < 4; ++q) {
            int kt = m0 / 16 + (q >> 1);
            size_t fi = ((size_t)(colg >> 5) * 128 + kt) * 512 +
                        ((q & 1) * 32 + (colg & 31)) * 8 + kh * 4;
            ushort4_t pk;
            pk.x = f2bf(acc[q * 4 + 0]);
            pk.y = f2bf(acc[q * 4 + 1]);
            pk.z = f2bf(acc[q * 4 + 2]);
            pk.w = f2bf(acc[q * 4 + 3]);
            *(ushort4_t*)(CF + fi) = pk;
        }
        float a1v = a_out[colg];
        float a2v = a_out[256 + colg];
        float* sbuf = (float*)As;
#pragma unroll
        for (int reg = 0; reg < 16; ++reg) {
            int rl = 4 * kh + (reg & 3) + 8 * (reg >> 2);
            float v1 = acc[reg] * a1v;
            float v2 = acc[reg] * a2v;
#pragma unroll
            for (int m = 1; m <= 16; m <<= 1) {
                v1 += __shfl_xor(v1, m, 64);
                v2 += __shfl_xor(v2, m, 64);
            }
            if (lm == 0) { sbuf[rl * 16 + wv] = v1; sbuf[rl * 16 + 8 + wv] = v2; }
        }
        __syncthreads();
        if (t < 32) {
            float s1 = 0.f, s2 = 0.f;
#pragma unroll
            for (int k = 0; k < 8; ++k) {
                s1 += sbuf[t * 16 + k];
                s2 += sbuf[t * 16 + 8 + k];
            }
            size_t ei = (size_t)b * Nn + m0 + t;
            E1p[ei] = __expf(s1);
            E1n[ei] = __expf(0.2f * s1);
            E2pn[ei] = make_float2(__expf(s2), __expf(0.2f * s2));
        }
    }
}

// ---------------- final GEMM with fused combine, BK=128, o-split x2 ----------------
__global__ __launch_bounds__(256) void gemm32_final_kernel(
        const float* __restrict__ pacc, const float* __restrict__ plsum,
        const float* __restrict__ lin, const float* __restrict__ b_lin,
        const unsigned short* __restrict__ BF, const float* __restrict__ b_ln,
        float* __restrict__ out) {
    int b = blockIdx.z, oc = blockIdx.y;
    int m0 = blockIdx.x * 32;
    int t = threadIdx.x;
    int wv = t >> 6, lane = t & 63;
    int lm = lane & 31, kh = lane >> 5;
    constexpr int nfk = 16;   // K = 256
    __shared__ __align__(16) unsigned short As[32][136];
    f32x16 acc = {};
    int sr = t >> 3, sc2 = (t & 7) * 16;
    int row = m0 + sr;
    int BN = Bb * Nn;
    size_t prow = (size_t)b * Nn + row;
    float li = 1.f / (plsum[prow] + plsum[prow + BN] + plsum[prow + 2 * BN] + plsum[prow + 3 * BN]);
    size_t ps4 = (size_t)Bb * Nn * 256;
    const unsigned short* bg = BF + (size_t)(oc * 4 + wv) * nfk * 512;
    for (int k0 = 0; k0 < 256; k0 += 128) {
        int o = k0 + sc2;
        size_t pidx = prow * 256 + o;
#pragma unroll
        for (int g = 0; g < 4; ++g) {
            float4 s4 = *(const float4*)(pacc + pidx + 4 * g);
#pragma unroll
            for (int k = 1; k < 4; ++k) {
                float4 q = *(const float4*)(pacc + k * ps4 + pidx + 4 * g);
                s4.x += q.x; s4.y += q.y; s4.z += q.z; s4.w += q.w;
            }
            float4 lv = *(const float4*)(lin + pidx + 4 * g);
            float4 bv = *(const float4*)(b_lin + o + 4 * g);
            ushort4_t pk;
            pk.x = f2bf(s4.x * li + lv.x + bv.x);
            pk.y = f2bf(s4.y * li + lv.y + bv.y);
            pk.z = f2bf(s4.z * li + lv.z + bv.z);
            pk.w = f2bf(s4.w * li + lv.w + bv.w);
            *(ushort4_t*)&As[sr][sc2 + 4 * g] = pk;
        }
        int kt0 = k0 >> 4;
        __syncthreads();
#pragma unroll
        for (int s = 0; s < 8; ++s) {
            short8 a0 = *(const short8*)&As[lm][s * 16 + kh * 8];
            short8 b0 = *(const short8*)(bg + (size_t)(kt0 + s) * 512 + lane * 8);
            acc = __builtin_amdgcn_mfma_f32_32x32x16_bf16(a0, b0, acc, 0, 0, 0);
        }
        __syncthreads();
    }
    float* C = out + (size_t)b * Nn * 256;
    int colg = oc * 128 + wv * 32 + lm;
    float bv = b_ln[colg];
#pragma unroll
    for (int reg = 0; reg < 16; ++reg) {
        int rl = 4 * kh + (reg & 3) + 8 * (reg >> 2);
        float v = fmaxf(acc[reg] + bv, 0.f);
        C[(size_t)(m0 + rl) * 256 + colg] = v;
    }
}

// ---------------- attention 32-row (R1-verified v9: 4-slot rotation + setprio) ----------------
template<int JLEN, int MODE, int SWAPXY>
__global__ __launch_bounds__(256, 4) void attn32_kernel(
        const unsigned short* __restrict__ hfrag,
        const unsigned* __restrict__ bits,
        const float* __restrict__ E1p, const float* __restrict__ E1n,
        const float2* __restrict__ E2pn,
        unsigned short* __restrict__ outbf, int ldo,
        float* __restrict__ pacc, float* __restrict__ plsum,
        int hshift) {
    constexpr int W = JLEN / 32, NC = JLEN / 64, ABS = W + 1;
    int it = SWAPXY ? blockIdx.y : blockIdx.x;
    int bh = SWAPXY ? blockIdx.x : blockIdx.y;
    int js = blockIdx.z;
    int b = bh >> hshift, hd = bh & ((1 << hshift) - 1);
    int i0 = it * 32, jbase = js * JLEN;
    int kt0 = js * (JLEN / 16);
    int t = threadIdx.x, lane = t & 63;
    int wv = t >> 6, lm = lane & 31, kh = lane >> 5;
    int ti = t & 31, jq = t >> 5;

    __shared__ unsigned ab[32 * ABS];
    __shared__ __align__(16) unsigned short ps[2][32][64];
    __shared__ float lred[32][9];
    __shared__ float linv[32];

    const unsigned* bb = bits + ((size_t)b * Nn + i0) * 64 + (jbase >> 5);
    for (int k = t; k < 32 * W; k += 256) {
        int r = k / W, w0 = k - r * W;
        ab[r * ABS + w0] = bb[(size_t)r * 64 + w0];
    }
    __syncthreads();

    float e1p = E1p[(size_t)bh * Nn + i0 + ti];
    float e1n = E1n[(size_t)bh * Nn + i0 + ti];
    const float4* e2base = (const float4*)(E2pn + (size_t)bh * Nn + jbase);

    const unsigned short* bg0 = hfrag + (size_t)bh * 524288 + (size_t)(wv * 2) * 128 * 512;
    const unsigned short* bg1 = bg0 + 128 * 512;

    f32x16 acc[2] = {};
    float lp0 = 0.f, lp1 = 0.f;
    short8 Bpp[4][2];

    auto loadBs = [&](int c, int s, int slot) {
        int kt = kt0 + c * 4 + s;
        Bpp[slot][0] = *(const short8*)(bg0 + (size_t)kt * 512 + lane * 8);
        Bpp[slot][1] = *(const short8*)(bg1 + (size_t)kt * 512 + lane * 8);
    };
    auto computeP = [&](int c, int buf) {
        int cj = c * 64;
        unsigned word = ab[ti * ABS + (cj >> 5) + (jq >> 2)];
        unsigned field = (word >> ((jq & 3) * 8)) & 0xffu;
        const float4* ep = e2base + ((cj + jq * 8) >> 1);
        unsigned pk[4];
#pragma unroll
        for (int u = 0; u < 4; ++u) {
            float4 q = ep[u];
            float p0 = fmaxf(e1p * q.x, e1n * q.y);
            p0 = ((field >> (2 * u)) & 1u) ? p0 : 0.f;
            float p1 = fmaxf(e1p * q.z, e1n * q.w);
            p1 = ((field >> (2 * u + 1)) & 1u) ? p1 : 0.f;
            if (u & 1) lp1 += p0 + p1; else lp0 += p0 + p1;
            __hip_bfloat162 hv = __float22bfloat162_rn(make_float2(p0, p1));
            pk[u] = *(unsigned*)&hv;
        }
        uint4 v; v.x = pk[0]; v.y = pk[1]; v.z = pk[2]; v.w = pk[3];
        *(uint4*)&ps[buf][ti][(jq ^ (ti & 7)) * 8] = v;
    };
    auto mfmaS = [&](int buf, int s, int slot) {
        int g = 2 * s + kh;
        short8 a0 = *(const short8*)&ps[buf][lm][(g ^ (lm & 7)) * 8];
        __builtin_amdgcn_s_setprio(1);
        acc[0] = __builtin_amdgcn_mfma_f32_32x32x16_bf16(a0, Bpp[slot][0], acc[0], 0, 0, 0);
        acc[1] = __builtin_amdgcn_mfma_f32_32x32x16_bf16(a0, Bpp[slot][1], acc[1], 0, 0, 0);
        __builtin_amdgcn_s_setprio(0);
    };

    computeP(0, 0);
    loadBs(0, 0, 0); loadBs(0, 1, 1); loadBs(0, 2, 2); loadBs(0, 3, 3);
    __syncthreads();
    for (int c = 0; c + 1 < NC; ++c) {
        int cb = c & 1, nb = cb ^ 1;
        computeP(c + 1, nb);
        mfmaS(cb, 0, 0);  loadBs(c + 1, 0, 0);
        mfmaS(cb, 1, 1);  loadBs(c + 1, 1, 1);
        mfmaS(cb, 2, 2);  loadBs(c + 1, 2, 2);
        mfmaS(cb, 3, 3);  loadBs(c + 1, 3, 3);
        __syncthreads();
    }
    {
        int cb = (NC - 1) & 1;
        mfmaS(cb, 0, 0);
        mfmaS(cb, 1, 1);
        mfmaS(cb, 2, 2);
        mfmaS(cb, 3, 3);
    }

    lred[ti][jq] = lp0 + lp1;
    __syncthreads();
    if (MODE == 0) {
        if (t < 32) {
            float s = 0.f;
#pragma unroll
            for (int k = 0; k < 8; ++k) s += lred[t][k];
            linv[t] = 1.f / s;
        }
        __syncthreads();
#pragma unroll
        for (int nt = 0; nt < 2; ++nt) {
            int o = wv * 64 + nt * 32 + lm;
#pragma unroll
            for (int reg = 0; reg < 16; ++reg) {
                int rl = 4 * kh + (reg & 3) + 8 * (reg >> 2);
                float v = acc[nt][reg] * linv[rl];
                v = v > 0.f ? v : expm1f(v);
                outbf[((size_t)b * Nn + i0 + rl) * ldo + (size_t)hd * Oo + o] = f2bf(v);
            }
        }
    } else {
        if (t < 32) {
            float s = 0.f;
#pragma unroll
            for (int k = 0; k < 8; ++k) s += lred[t][k];
            plsum[((size_t)js * Bb + b) * Nn + i0 + t] = s;
        }
        float* pa = pacc + (((size_t)js * Bb + b) * Nn) * 256;
#pragma unroll
        for (int nt = 0; nt < 2; ++nt) {
            int o = wv * 64 + nt * 32 + lm;
#pragma unroll
            for (int reg = 0; reg < 16; ++reg) {
                int rl = 4 * kh + (reg & 3) + 8 * (reg >> 2);
                pa[(size_t)(i0 + rl) * 256 + o] = acc[nt][reg];
            }
        }
    }
}

// ---------------- attention 64-row (R6/R9-verified): halves B/e2 L2 traffic ----------------
template<int JLEN, int MODE, int SWAPXY>
__global__ __launch_bounds__(256, 2) void attn64_kernel(
        const unsigned short* __restrict__ hfrag,
        const unsigned* __restrict__ bits,
        const float* __restrict__ E1p, const float* __restrict__ E1n,
        const float2* __restrict__ E2pn,
        unsigned short* __restrict__ outbf, int ldo,
        float* __restrict__ pacc, float* __restrict__ plsum,
        int hshift) {
    constexpr int W = JLEN / 32, NC = JLEN / 64, ABS = W + 1;
    int it = SWAPXY ? blockIdx.y : blockIdx.x;
    int bh = SWAPXY ? blockIdx.x : blockIdx.y;
    int js = blockIdx.z;
    int b = bh >> hshift, hd = bh & ((1 << hshift) - 1);
    int i0 = it * 64, jbase = js * JLEN;
    int kt0 = js * (JLEN / 16);
    int t = threadIdx.x, lane = t & 63;
    int wv = t >> 6, lm = lane & 31, kh = lane >> 5;
    int ti = t & 31, jq = t >> 5;

    __shared__ unsigned ab[64 * ABS];
    __shared__ __align__(16) unsigned short ps[2][64][64];
    __shared__ float lred[64][9];
    __shared__ float linv[64];

    const unsigned* bb = bits + ((size_t)b * Nn + i0) * 64 + (jbase >> 5);
    for (int k = t; k < 64 * W; k += 256) {
        int r = k / W, w0 = k - r * W;
        ab[r * ABS + w0] = bb[(size_t)r * 64 + w0];
    }
    __syncthreads();

    float e1pA = E1p[(size_t)bh * Nn + i0 + ti];
    float e1nA = E1n[(size_t)bh * Nn + i0 + ti];
    float e1pB = E1p[(size_t)bh * Nn + i0 + 32 + ti];
    float e1nB = E1n[(size_t)bh * Nn + i0 + 32 + ti];
    const float4* e2base = (const float4*)(E2pn + (size_t)bh * Nn + jbase);

    const unsigned short* bg0 = hfrag + (size_t)bh * 524288 + (size_t)(wv * 2) * 128 * 512;
    const unsigned short* bg1 = bg0 + 128 * 512;

    f32x16 acc[4] = {};
    float lpA = 0.f, lpB = 0.f;
    short8 Bpp[4][2];

    auto loadBs = [&](int c, int s, int slot) {
        int kt = kt0 + c * 4 + s;
        Bpp[slot][0] = *(const short8*)(bg0 + (size_t)kt * 512 + lane * 8);
        Bpp[slot][1] = *(const short8*)(bg1 + (size_t)kt * 512 + lane * 8);
    };
    auto computeP = [&](int c, int buf) {
        int cj = c * 64;
        int wi = (cj >> 5) + (jq >> 2);
        unsigned wordA = ab[ti * ABS + wi];
        unsigned wordB = ab[(ti + 32) * ABS + wi];
        unsigned fieldA = (wordA >> ((jq & 3) * 8)) & 0xffu;
        unsigned fieldB = (wordB >> ((jq & 3) * 8)) & 0xffu;
        const float4* ep = e2base + ((cj + jq * 8) >> 1);
        unsigned pkA[4], pkB[4];
#pragma unroll
        for (int u = 0; u < 4; ++u) {
            float4 q = ep[u];   // shared between both rows
            float a0v = fmaxf(e1pA * q.x, e1nA * q.y);
            a0v = ((fieldA >> (2 * u)) & 1u) ? a0v : 0.f;
            float a1v = fmaxf(e1pA * q.z, e1nA * q.w);
            a1v = ((fieldA >> (2 * u + 1)) & 1u) ? a1v : 0.f;
            lpA += a0v + a1v;
            float b0v = fmaxf(e1pB * q.x, e1nB * q.y);
            b0v = ((fieldB >> (2 * u)) & 1u) ? b0v : 0.f;
            float b1v = fmaxf(e1pB * q.z, e1nB * q.w);
            b1v = ((fieldB >> (2 * u + 1)) & 1u) ? b1v : 0.f;
            lpB += b0v + b1v;
            __hip_bfloat162 hA = __float22bfloat162_rn(make_float2(a0v, a1v));
            __hip_bfloat162 hB = __float22bfloat162_rn(make_float2(b0v, b1v));
            pkA[u] = *(unsigned*)&hA;
            pkB[u] = *(unsigned*)&hB;
        }
        int col = (jq ^ (ti & 7)) * 8;
        uint4 vA; vA.x = pkA[0]; vA.y = pkA[1]; vA.z = pkA[2]; vA.w = pkA[3];
        uint4 vB; vB.x = pkB[0]; vB.y = pkB[1]; vB.z = pkB[2]; vB.w = pkB[3];
        *(uint4*)&ps[buf][ti][col] = vA;
        *(uint4*)&ps[buf][ti + 32][col] = vB;
    };
    auto mfmaS = [&](int buf, int s, int slot) {
        int g = 2 * s + kh;
        int col = (g ^ (lm & 7)) * 8;
        short8 a0 = *(const short8*)&ps[buf][lm][col];
        short8 a1 = *(const short8*)&ps[buf][32 + lm][col];
        __builtin_amdgcn_s_setprio(1);
        acc[0] = __builtin_amdgcn_mfma_f32_32x32x16_bf16(a0, Bpp[slot][0], acc[0], 0, 0, 0);
        acc[1] = __builtin_amdgcn_mfma_f32_32x32x16_bf16(a0, Bpp[slot][1], acc[1], 0, 0, 0);
        acc[2] = __builtin_amdgcn_mfma_f32_32x32x16_bf16(a1, Bpp[slot][0], acc[2], 0, 0, 0);
        acc[3] = __builtin_amdgcn_mfma_f32_32x32x16_bf16(a1, Bpp[slot][1], acc[3], 0, 0, 0);
        __builtin_amdgcn_s_setprio(0);
    };

    computeP(0, 0);
    loadBs(0, 0, 0); loadBs(0, 1, 1); loadBs(0, 2, 2); loadBs(0, 3, 3);
    __syncthreads();
    for (int c = 0; c + 1 < NC; ++c) {
        int cb = c & 1, nb = cb ^ 1;
        computeP(c + 1, nb);
        mfmaS(cb, 0, 0);  loadBs(c + 1, 0, 0);
        mfmaS(cb, 1, 1);  loadBs(c + 1, 1, 1);
        mfmaS(cb, 2, 2);  loadBs(c + 1, 2, 2);
        mfmaS(cb, 3, 3);  loadBs(c + 1, 3, 3);
        __syncthreads();
    }
    {
        int cb = (NC - 1) & 1;
        mfmaS(cb, 0, 0);
        mfmaS(cb, 1, 1);
        mfmaS(cb, 2, 2);
        mfmaS(cb, 3, 3);
    }

    lred[ti][jq] = lpA;
    lred[ti + 32][jq] = lpB;
    __syncthreads();
    if (MODE == 0) {
        if (t < 64) {
            float s = 0.f;
#pragma unroll
            for (int k = 0; k < 8; ++k) s += lred[t][k];
            linv[t] = 1.f / s;
        }
        __syncthreads();
#pragma unroll
        for (int ih = 0; ih < 2; ++ih) {
#pragma unroll
            for (int nt = 0; nt < 2; ++nt) {
                int o = wv * 64 + nt * 32 + lm;
#pragma unroll
                for (int reg = 0; reg < 16; ++reg) {
                    int rl = 4 * kh + (reg & 3) + 8 * (reg >> 2);
                    int row = ih * 32 + rl;
                    float v = acc[ih * 2 + nt][reg] * linv[row];
                    v = v > 0.f ? v : expm1f(v);
                    outbf[((size_t)b * Nn + i0 + row) * ldo + (size_t)hd * Oo + o] = f2bf(v);
                }
            }
        }
    } else {
        if (t < 64) {
            float s = 0.f;
#pragma unroll
            for (int k = 0; k < 8; ++k) s += lred[t][k];
            plsum[((size_t)js * Bb + b) * Nn + i0 + t] = s;
        }
        float* pa = pacc + (((size_t)js * Bb + b) * Nn) * 256;
#pragma unroll
        for (int ih = 0; ih < 2; ++ih) {
#pragma unroll
            for (int nt = 0; nt < 2; ++nt) {
                int o = wv * 64 + nt * 32 + lm;
#pragma unroll
                for (int reg = 0; reg < 16; ++reg) {
                    int rl = 4 * kh + (reg & 3) + 8 * (reg >> 2);
                    int row = ih * 32 + rl;
                    pa[(size_t)(i0 + row) * 256 + o] = acc[ih * 2 + nt][reg];
                }
            }
        }
    }
}

extern "C" void kernel_launch(void* const* d_in, const int* in_sizes, int n_in,
                              void* d_out, int out_size, void* d_ws, size_t ws_size,
                              hipStream_t stream) {
    const float* x       = (const float*)d_in[0];
    const float* adj     = (const float*)d_in[1];
    const float* W_heads = (const float*)d_in[3];
    const float* a_heads = (const float*)d_in[4];
    const float* W_out   = (const float*)d_in[5];
    const float* a_out   = (const float*)d_in[6];
    const float* W_lin   = (const float*)d_in[7];
    const float* b_lin   = (const float*)d_in[8];
    const float* W_ln    = (const float*)d_in[9];
    const float* b_ln    = (const float*)d_in[10];

    char* w = (char*)d_ws;
    float* pacc     = (float*)(w);                    // 4x4 MB (sh partials)
    float* lin      = (float*)(w + 33554432);
    float* E1p_mh   = (float*)(w + 41943040);
    float* E1n_mh   = (float*)(w + 42074112);
    float2* E2pn_mh = (float2*)(w + 42205184);
    float* E1p_sh   = (float*)(w + 42467328);
    float* E1n_sh   = (float*)(w + 42483712);
    float2* E2pn_sh = (float2*)(w + 42500096);
    unsigned long long* bits = (unsigned long long*)(w + 42532864);
    unsigned short* x_bf  = (unsigned short*)(w + 43581440);
    unsigned short* WhF   = (unsigned short*)(w + 49872896);
    unsigned short* WoF   = (unsigned short*)(w + 53018624);
    unsigned short* WlF   = (unsigned short*)(w + 54067200);
    unsigned short* WnF   = (unsigned short*)(w + 55115776);
    unsigned short* hfrag = (unsigned short*)(w + 55246848);   // 16 MB
    unsigned short* h2frag= (unsigned short*)(w + 72024064);   // 2 MB
    unsigned short* x1_bf = (unsigned short*)(w + 74121216);
    float* plsum = E1p_mh;

    // 0) merged prep: adjbits + x cast + all weight frags (1 launch)
    prep_misc_kernel<<<37152, 256, 0, stream>>>(
        adj, bits, x, x_bf, W_heads, WhF, W_out, WoF, W_lin, WlF, W_ln, WnF);

    // 1) h = x @ W_heads -> hfrag + fused mh scores/exp (z-major: XCD = z%8)
    gemm32_kernel<1><<<dim3(Bb * Hh, Nn / 32, 1), 256, 0, stream>>>(
        x_bf, Ff, (long long)Nn * Ff, 3, WhF, 384LL * 512, 7,
        nullptr, 0, hfrag, 524288, Nn, nullptr, 1,
        a_heads, 7, E1p_mh, E1n_mh, E2pn_mh);
    // 2) multihead attention + elu -> x1_bf  (64-row tiles halve L2 B-traffic; XCD = bh%8)
    attn64_kernel<2048, 0, 1><<<dim3(Bb * Hh, Nn / 64, 1), 256, 0, stream>>>(
        hfrag, (const unsigned*)bits, E1p_mh, E1n_mh, E2pn_mh,
        x1_bf, Hh * Oo, nullptr, nullptr, 3);
    // 3) fused dual GEMM: h2frag (+sh scores) and lin — 8-wave blocks
    gemm32_dual_kernel<<<dim3(Nn / 32, 2, Bb), 512, 0, stream>>>(
        x1_bf, Hh * Oo, (long long)Nn * Hh * Oo, WoF, h2frag, lin,
        a_out, E1p_sh, E1n_sh, E2pn_sh);
    // 4) single-head attention, 4-way j-split partials (32-row, 2 blocks/CU)
    attn32_kernel<512, 1, 0><<<dim3(Nn / 32, Bb, 4), 256, 0, stream>>>(
        h2frag, (const unsigned*)bits, E1p_sh, E1n_sh, E2pn_sh,
        nullptr, 0, pacc, plsum, 0);
    // 5) final GEMM with fused combine (o-split x2) -> d_out
    gemm32_final_kernel<<<dim3(Nn / 32, 2, Bb), 256, 0, stream>>>(
        pacc, plsum, lin, b_lin, WnF, b_ln, (float*)d_out);
}